// Round 1
// baseline (16214.906 us; speedup 1.0000x reference)
//
#include <hip/hip_runtime.h>

// PRPN eval forward for MI355X. All float inputs are FP32, ids int32.
// Output = [y (T*B*D) | mask (T*B)] fp32.
//
// R6 vs R5: 2-phase pipelined scan (was 3 full grid barriers/step).
//  - Layer1 lags layer0 by half a step: E-phase runs L0(s) | L1(s-1) | PR(s-2)
//    on 96 per-b wgs IN PARALLEL (they were serialized across phases before).
//  - O-phase runs ALL GEMVs (from h0(s) and h1(s-1)) on 160 wgs; second x
//    vector prefetched to registers under the first half's FMAs.
//  - Barriers: 577 -> 387, and they are producer-consumer gates (fan-in 96 /
//    160, 2-level monotone counters) instead of full 256-wg barriers.
//  - HNEW1 double-buffered by parity (second buffer reuses the dead O_H1
//    conv-activation region; it is write-before-read so no zeroing needed).
//  - GEMV partials: 8 k-groups pair-combined via shfl_down(32) -> 4 LDS rows,
//    so 24 cols fit one reduce chunk (red = 4*24*33 floats).

#define TT 192
#define TB 6144
#define NGV 160

constexpr size_t O_EMB    = 0;          // T*B*384 fp32
constexpr size_t O_IH0LN  = 2359296;    // T*B*1536 (raw then LN'd in place)
constexpr size_t O_KEY0E  = 11796480;   // T*B*384
constexpr size_t O_MG     = 14155776;   // T*B*15
constexpr size_t O_MGN    = 14247936;   // T*B*15
constexpr size_t O_H1     = 14340096;   // B*T x 384 conv acts (pre-scan only)
constexpr size_t O_GATEA  = 16699392;   // B*T
constexpr size_t O_GATEB  = 16705536;   // B*T
constexpr size_t O_OUTHS  = 16711680;   // T*B x 768 (h | sel)
constexpr size_t O_MEMH0  = 21430272;   // state (zeroed): B x 15 x 384 each
constexpr size_t O_MEMC0  = 21614592;
constexpr size_t O_MEMH1  = 21798912;
constexpr size_t O_MEMC1  = 21983232;
constexpr size_t O_PMEM   = 22167552;
constexpr size_t O_P0     = 22351872;   // B x 15 x 1536
constexpr size_t O_P1     = 23089152;
constexpr size_t O_HNEW0  = 23826432;   // B x 384
constexpr size_t O_HNEW1A = 23838720;   // h1 parity buffer 0
constexpr size_t O_HNEW1B = 14340096;   // h1 parity buffer 1 (= O_H1, reused)
constexpr size_t O_IH1RAW = 23851008;   // B x 1536
constexpr size_t O_KEY1H  = 23900160;
constexpr size_t O_KEY0MH = 23912448;
constexpr size_t O_KEY1MH = 23924736;
constexpr size_t O_PKEYH  = 23937024;
constexpr size_t O_PKEYMH = 23949312;   // 2 x B x 384 (ping-pong)
constexpr size_t O_BAR    = 23973888;   // barrier counters (544 u32, padded)
constexpr size_t O_WSEND  = 23974432;

// barrier u32 layout inside O_BAR
#define BO_GRP_E  0    // 6 lines (g*16)
#define BO_ROOT_E 96
#define BO_GEN_E  112
#define BO_GRP_O  128  // 10 lines (128 + g*16)
#define BO_ROOT_O 288
#define BO_GEN_O  304

__device__ __forceinline__ float sigmoidf(float x) { return 1.f / (1.f + expf(-x)); }

// LLC-coherent (bypass per-XCD L2) relaxed accessors for cross-wg exchange.
__device__ __forceinline__ float ldx(const float* p) {
  return __hip_atomic_load(p, __ATOMIC_RELAXED, __HIP_MEMORY_SCOPE_AGENT);
}
__device__ __forceinline__ void stx(float* p, float v) {
  __hip_atomic_store(p, v, __ATOMIC_RELAXED, __HIP_MEMORY_SCOPE_AGENT);
}
__device__ __forceinline__ unsigned ldu(const unsigned* p) {
  return __hip_atomic_load(p, __ATOMIC_RELAXED, __HIP_MEMORY_SCOPE_AGENT);
}

constexpr float BN_SC = 0.9999950000374997f;       // 1/sqrt(1+1e-5)
constexpr float INV_SQRT_H = 0.05103103630798288f; // 1/sqrt(384)

__device__ __forceinline__ float blockSum(float v, float* red) {
#pragma unroll
  for (int off = 32; off > 0; off >>= 1) v += __shfl_down(v, off, 64);
  __syncthreads();
  if ((threadIdx.x & 63) == 0) red[threadIdx.x >> 6] = v;
  __syncthreads();
  return red[0] + red[1] + red[2] + red[3];
}

// ---------------------------------------------------------------- k_zero
__global__ __launch_bounds__(256) void k_zero(float* p, int n) {
  int i = blockIdx.x * 256 + threadIdx.x;
  int stride = gridDim.x * 256;
  for (; i < n; i += stride) p[i] = 0.f;
}

// ---------------------------------------------------------------- k_emb (+mask)
__global__ __launch_bounds__(256) void k_emb(const int* ids, const float* emb_w,
                                             float* emb, float* out) {
  size_t idx = (size_t)blockIdx.x * 256 + threadIdx.x;
  size_t stride = (size_t)gridDim.x * 256;
  for (size_t i = idx; i < (size_t)TB * 384; i += stride) {
    size_t tb = i / 384, d = i - tb * 384;
    int id = ids[tb];
    emb[i] = emb_w[(size_t)id * 384 + d];
    if (i < TB) out[(size_t)TB * 384 + i] = (ids[i] != 0) ? 1.f : 0.f;
  }
}

// ---------------------------------------------------------------- k_conv (im2col GEMM)
__global__ __launch_bounds__(256) void k_conv(const float* emb, const float* W1, const float* cbias,
                                              const float* bng, const float* bnb, float* h1) {
  __shared__ float As[32][68];
  __shared__ float Bs[32][68];
  int n0 = blockIdx.x * 64, m0 = blockIdx.y * 64;
  int tid = threadIdx.x;
  float acc[4][4] = {};
  int mi = tid >> 3, kq = tid & 7;
  int ni = tid >> 2, kb = tid & 3;
  for (int kk = 0; kk < 2304; kk += 32) {
    int kc = kk / 384, dbase = kk - kc * 384;
    __syncthreads();
#pragma unroll
    for (int p = 0; p < 2; ++p) {
      int m = m0 + mi + 32 * p;
      int b = m / 192, t = m - b * 192;
      int tt = t + kc - 5;
      float4 v = {0.f, 0.f, 0.f, 0.f};
      if (tt >= 0) v = *(const float4*)(emb + ((size_t)tt * 32 + b) * 384 + dbase + kq * 4);
      As[kq * 4 + 0][mi + 32 * p] = v.x; As[kq * 4 + 1][mi + 32 * p] = v.y;
      As[kq * 4 + 2][mi + 32 * p] = v.z; As[kq * 4 + 3][mi + 32 * p] = v.w;
    }
#pragma unroll
    for (int i = 0; i < 8; ++i) {
      int d = dbase + kb * 8 + i;
      Bs[kb * 8 + i][ni] = W1[(size_t)(n0 + ni) * 2304 + d * 6 + kc];
    }
    __syncthreads();
    int ty = tid >> 4, tx = tid & 15;
#pragma unroll
    for (int k = 0; k < 32; ++k) {
      float4 a = *(const float4*)(&As[k][ty * 4]);
      float4 bv = *(const float4*)(&Bs[k][tx * 4]);
      acc[0][0] += a.x * bv.x; acc[0][1] += a.x * bv.y; acc[0][2] += a.x * bv.z; acc[0][3] += a.x * bv.w;
      acc[1][0] += a.y * bv.x; acc[1][1] += a.y * bv.y; acc[1][2] += a.y * bv.z; acc[1][3] += a.y * bv.w;
      acc[2][0] += a.z * bv.x; acc[2][1] += a.z * bv.y; acc[2][2] += a.z * bv.z; acc[2][3] += a.z * bv.w;
      acc[3][0] += a.w * bv.x; acc[3][1] += a.w * bv.y; acc[3][2] += a.w * bv.z; acc[3][3] += a.w * bv.w;
    }
  }
  int ty = tid >> 4, tx = tid & 15;
#pragma unroll
  for (int i = 0; i < 4; ++i) {
    int m = m0 + ty * 4 + i;
#pragma unroll
    for (int j = 0; j < 4; ++j) {
      int n = n0 + tx * 4 + j;
      float v = acc[i][j] + cbias[n];
      v = bng[n] * v * BN_SC + bnb[n];
      h1[(size_t)m * 384 + n] = fmaxf(v, 0.f);
    }
  }
}

// ---------------------------------------------------------------- k_gate
__global__ __launch_bounds__(256) void k_gate(const float* h1, const float* w2, const float* b2,
                                              float* gA, float* gB) {
  __shared__ float red[8];
  int bt = blockIdx.x, tid = threadIdx.x;
  float v0 = 0.f, v1 = 0.f;
  if (tid < 192) {
    v0 = h1[(size_t)bt * 384 + tid] * w2[tid];
    v1 = h1[(size_t)bt * 384 + 192 + tid] * w2[192 + tid];
  }
  float s0 = blockSum(v0, red);
  float s1 = blockSum(v1, red);
  if (tid == 0) {
    gA[bt] = 1.f / (1.f + expf(-(s0 + b2[0])));
    gB[bt] = 1.f / (1.f + expf(-(s1 + b2[1])));
  }
}

// ---------------------------------------------------------------- k_mg (hard gates + cumprod)
__global__ __launch_bounds__(256) void k_mg(const float* gA, const float* gB, float* mg, float* mgn) {
  int idx = blockIdx.x * 256 + threadIdx.x;
  if (idx >= TB) return;
  int t = idx >> 5, b = idx & 31;
  float g = gA[b * 192 + t], gn = gB[b * 192 + t];
  float p = 1.f, pn = 1.f;
  for (int k = 0; k < 15; ++k) {
    float ghat = (k <= t) ? gA[b * 192 + t - k] : 1e9f;
    float u = fminf(fmaxf((g - ghat) / 0.1f * 2.f + 1.f, -1.f), 1.f);
    float un = fminf(fmaxf((gn - ghat) / 0.1f * 2.f + 1.f, -1.f), 1.f);
    p *= (u + 1.f) * 0.5f;
    pn *= (un + 1.f) * 0.5f;
    mg[(size_t)idx * 15 + k] = p;
    mgn[(size_t)idx * 15 + k] = pn;
  }
}

// ---------------------------------------------------------------- k_gemm (generic)
__global__ __launch_bounds__(256) void k_gemm(const float* A, int lda, const float* W, int ldw,
                                              const float* bias, float* Cf, int ldc, int K, int mode,
                                              const float* bng, const float* bnb, float* Cb) {
  __shared__ float As[32][68];
  __shared__ float Bs[32][68];
  int n0 = blockIdx.x * 64, m0 = blockIdx.y * 64;
  int tid = threadIdx.x;
  float acc[4][4] = {};
  int mi = tid >> 3, kq = tid & 7;
  int ni = tid >> 2, kb = tid & 3;
  for (int kk = 0; kk < K; kk += 32) {
    __syncthreads();
#pragma unroll
    for (int p = 0; p < 2; ++p) {
      int m = m0 + mi + 32 * p;
      float4 v = *(const float4*)(A + (size_t)m * lda + kk + kq * 4);
      As[kq * 4 + 0][mi + 32 * p] = v.x; As[kq * 4 + 1][mi + 32 * p] = v.y;
      As[kq * 4 + 2][mi + 32 * p] = v.z; As[kq * 4 + 3][mi + 32 * p] = v.w;
    }
    {
      const float* wp = W + (size_t)(n0 + ni) * ldw + kk + kb * 8;
      float4 q0 = *(const float4*)(wp);
      float4 q1 = *(const float4*)(wp + 4);
      Bs[kb * 8 + 0][ni] = q0.x; Bs[kb * 8 + 1][ni] = q0.y;
      Bs[kb * 8 + 2][ni] = q0.z; Bs[kb * 8 + 3][ni] = q0.w;
      Bs[kb * 8 + 4][ni] = q1.x; Bs[kb * 8 + 5][ni] = q1.y;
      Bs[kb * 8 + 6][ni] = q1.z; Bs[kb * 8 + 7][ni] = q1.w;
    }
    __syncthreads();
    int ty = tid >> 4, tx = tid & 15;
#pragma unroll
    for (int k = 0; k < 32; ++k) {
      float4 a = *(const float4*)(&As[k][ty * 4]);
      float4 bv = *(const float4*)(&Bs[k][tx * 4]);
      acc[0][0] += a.x * bv.x; acc[0][1] += a.x * bv.y; acc[0][2] += a.x * bv.z; acc[0][3] += a.x * bv.w;
      acc[1][0] += a.y * bv.x; acc[1][1] += a.y * bv.y; acc[1][2] += a.y * bv.z; acc[1][3] += a.y * bv.w;
      acc[2][0] += a.z * bv.x; acc[2][1] += a.z * bv.y; acc[2][2] += a.z * bv.z; acc[2][3] += a.z * bv.w;
      acc[3][0] += a.w * bv.x; acc[3][1] += a.w * bv.y; acc[3][2] += a.w * bv.z; acc[3][3] += a.w * bv.w;
    }
  }
  int ty = tid >> 4, tx = tid & 15;
#pragma unroll
  for (int i = 0; i < 4; ++i) {
    int m = m0 + ty * 4 + i;
#pragma unroll
    for (int j = 0; j < 4; ++j) {
      int n = n0 + tx * 4 + j;
      float v = acc[i][j];
      if (bias) v += bias[n];
      if (mode == 0) Cf[(size_t)m * ldc + n] = v;
      else Cb[(size_t)m * ldc + n] = tanhf(bng[n] * v * BN_SC + bnb[n]);
    }
  }
}

// ---------------------------------------------------------------- k_ln_rows
__global__ __launch_bounds__(256) void k_ln_rows(float* X, const float* g, const float* bt) {
  __shared__ float red[8];
  float* x = X + (size_t)blockIdx.x * 1536;
  int tid = threadIdx.x;
  float ps = 0.f;
  for (int i = tid; i < 1536; i += 256) ps += x[i];
  float mu = blockSum(ps, red) * (1.f / 1536.f);
  ps = 0.f;
  for (int i = tid; i < 1536; i += 256) { float d = x[i] - mu; ps += d * d; }
  float inv = 1.f / (sqrtf(blockSum(ps, red) * (1.f / 1535.f)) + 1e-6f);
  for (int i = tid; i < 1536; i += 256) x[i] = g[i] * (x[i] - mu) * inv + bt[i];
}

// ---------------------------------------------------------------- scan kernel
struct ScanArgs {
  float* ws;
  const float *r_whh, *r_bhh, *r_lnhh_g, *r_lnhh_b, *r_lnih_g, *r_lnih_b;
  const float *r_lnc_g, *r_lnc_b, *r_wih, *r_bih, *r_proj_w, *r_proj_b;
  const float *p_proj_w, *p_proj_b;
};

struct GJob { const float* W; int ldw; int koff; const float* bias; float* dst; int rstride; int ncols; };

__device__ __forceinline__ void resolveJob(const GJob* J, int col, const float*& W, int& ldw, int& koff,
                                           const float*& bias, float*& dst, int& rstride, int& cc) {
  int c = col;
#pragma unroll
  for (int j = 0; j < 4; ++j) {
    if (c < J[j].ncols) {
      W = J[j].W; ldw = J[j].ldw; koff = J[j].koff; bias = J[j].bias;
      dst = J[j].dst; rstride = J[j].rstride; cc = c; return;
    }
    c -= J[j].ncols;
  }
  W = J[0].W; ldw = J[0].ldw; koff = J[0].koff; bias = J[0].bias;
  dst = J[0].dst; rstride = J[0].rstride; cc = 0;
}

// producer-consumer gate: 2-level monotone counters, all relaxed.
__device__ __forceinline__ void arrive2(unsigned* bar, int grpOff, int rootOff, int genOff,
                                        int g, int ngroups, unsigned s) {
  unsigned a = __hip_atomic_fetch_add(bar + grpOff + g * 16, 1u, __ATOMIC_RELAXED, __HIP_MEMORY_SCOPE_AGENT);
  if (a == s * 16u + 15u) {
    unsigned r = __hip_atomic_fetch_add(bar + rootOff, 1u, __ATOMIC_RELAXED, __HIP_MEMORY_SCOPE_AGENT);
    if (r == s * (unsigned)ngroups + (unsigned)(ngroups - 1))
      __hip_atomic_store(bar + genOff, s + 1u, __ATOMIC_RELAXED, __HIP_MEMORY_SCOPE_AGENT);
  }
}
__device__ __forceinline__ void waitgen(const unsigned* bar, int genOff, unsigned tgt) {
  while (ldu(bar + genOff) < tgt) __builtin_amdgcn_s_sleep(2);
}

// one GEMV half: cols [c0,c1) of the 4-job set, x in registers (48/thread),
// 8 k-groups pair-combined via shfl -> red[4][nch][33] -> stx stores.
__device__ void gemv_half(const GJob* J, int NC, int gwg, const float* xr, float* red) {
  const int tid = threadIdx.x;
  const int b = tid & 31, cg = tid >> 5;
  const int c0 = (gwg * NC) / NGV, c1 = ((gwg + 1) * NC) / NGV;
  const int nch = c1 - c0;
  for (int ci = 0; ci < nch; ++ci) {
    const float* W; int ldw, koff; const float* bias; float* dst; int rstride; int cc;
    resolveJob(J, c0 + ci, W, ldw, koff, bias, dst, rstride, cc);
    const float* wr = W + (size_t)cc * ldw + koff + cg * 48;
    float a = 0.f;
#pragma unroll
    for (int q = 0; q < 12; ++q) {
      float4 w = *(const float4*)(wr + q * 4);
      a += w.x * xr[q * 4 + 0] + w.y * xr[q * 4 + 1]
         + w.z * xr[q * 4 + 2] + w.w * xr[q * 4 + 3];
    }
    a += __shfl_down(a, 32, 64);
    if ((cg & 1) == 0) red[((cg >> 1) * nch + ci) * 33 + b] = a;
  }
  __syncthreads();
  const int pairs = nch * 32;
  for (int pi = tid; pi < pairs; pi += 256) {
    int bb = pi / nch, ci = pi - bb * nch;
    float ssum = 0.f;
#pragma unroll
    for (int g2 = 0; g2 < 4; ++g2) ssum += red[(g2 * nch + ci) * 33 + bb];
    const float* W; int ldw, koff; const float* bias; float* dst; int rstride; int cc;
    resolveJob(J, c0 + ci, W, ldw, koff, bias, dst, rstride, cc);
    if (bias) ssum += bias[cc];
    stx(dst + (size_t)bb * rstride + cc, ssum);
  }
  __syncthreads();
}

// per-batch LSTM layer: attention (msoftmax, hard gate), P-cache combine,
// LayerNorms, cell, LN(c), memory append.
__device__ void per_b_layer(int layer, int t, int b, const ScanArgs& A, float* sm) {
  float* ws = A.ws;
  const int tid = threadIdx.x;
  const size_t tb = (size_t)t * 32 + b;
  float* memh = ws + (layer ? O_MEMH1 : O_MEMH0) + (size_t)b * 15 * 384;
  float* memc = ws + (layer ? O_MEMC1 : O_MEMC0) + (size_t)b * 15 * 384;
  float* P = ws + (layer ? O_P1 : O_P0) + (size_t)b * 15 * 1536;
  float* keyl = sm; float* logit = sm + 384; float* att = sm + 400; float* red = sm + 416;
  float* ghh = sm + 448; float* gih = sm + 1984; float* selc = sm + 3520;
  float* cnew = sm + 3904; float* ogat = sm + 4288;

  for (int h = tid; h < 384; h += 256) {
    float k1, k2;
    if (layer == 0) { k1 = ws[O_KEY0E + tb * 384 + h]; k2 = ldx(ws + O_KEY0MH + (size_t)b * 384 + h); }
    else { k1 = ldx(ws + O_KEY1H + (size_t)b * 384 + h); k2 = ldx(ws + O_KEY1MH + (size_t)b * 384 + h); }
    keyl[h] = k1 + k2;
  }
  // prefetch the gate-input vector early (hides LLC / stream latency under
  // the attention chain). layer0: IH0LN already LN'd; layer1: raw, LN below.
  if (layer) {
    for (int n = tid; n < 1536; n += 256) gih[n] = ldx(ws + O_IH1RAW + (size_t)b * 1536 + n);
  } else {
    for (int n = tid; n < 1536; n += 256) gih[n] = ws[O_IH0LN + tb * 1536 + n];
  }
  __syncthreads();
  {
    int s = tid >> 4, l = tid & 15;
    if (s < 15) {
      const float* mh = memh + ((t + s) % 15) * 384;
      float p = 0.f;
      for (int k = l; k < 384; k += 16) p += mh[k] * keyl[k];
      p += __shfl_down(p, 8, 64); p += __shfl_down(p, 4, 64);
      p += __shfl_down(p, 2, 64); p += __shfl_down(p, 1, 64);
      if (l == 0) logit[s] = p * INV_SQRT_H;
    }
  }
  __syncthreads();
  if (tid == 0) {
    const float* mgp = ws + O_MG + tb * 15;
    float m = logit[0];
    for (int i = 1; i < 15; ++i) m = fmaxf(m, logit[i]);
    float sum = 0.f;
    for (int i = 0; i < 15; ++i) { float e = expf(logit[i] - m) * mgp[i]; att[i] = e; sum += e; }
    float inv = 1.f / (sum + 1e-8f);
    for (int i = 0; i < 15; ++i) att[i] *= inv;
  }
  __syncthreads();
  float av[15]; int pidx[15];
#pragma unroll
  for (int i = 0; i < 15; ++i) { av[i] = att[i]; pidx[i] = (t + i) % 15; }
  const float* bhh = A.r_bhh + layer * 1536;
  for (int n = tid; n < 1536; n += 256) {
    float acc = bhh[n];
#pragma unroll
    for (int i = 0; i < 15; ++i) acc += av[i] * ldx(P + (size_t)pidx[i] * 1536 + n);
    ghh[n] = acc;
  }
  for (int h = tid; h < 384; h += 256) {
    float acc = 0.f;
#pragma unroll
    for (int i = 0; i < 15; ++i) acc += av[i] * memc[pidx[i] * 384 + h];
    selc[h] = acc;
  }
  __syncthreads();
  float ps = 0.f;
  for (int n = tid; n < 1536; n += 256) ps += ghh[n];
  float mu_hh = blockSum(ps, red) * (1.f / 1536.f);
  ps = 0.f;
  for (int n = tid; n < 1536; n += 256) { float d = ghh[n] - mu_hh; ps += d * d; }
  float inv_hh = 1.f / (sqrtf(blockSum(ps, red) * (1.f / 1535.f)) + 1e-6f);
  float mu_ih = 0.f, inv_ih = 0.f;
  if (layer) {
    ps = 0.f;
    for (int n = tid; n < 1536; n += 256) ps += gih[n];
    mu_ih = blockSum(ps, red) * (1.f / 1536.f);
    ps = 0.f;
    for (int n = tid; n < 1536; n += 256) { float d = gih[n] - mu_ih; ps += d * d; }
    inv_ih = 1.f / (sqrtf(blockSum(ps, red) * (1.f / 1535.f)) + 1e-6f);
  }
  const float *hg = A.r_lnhh_g + layer * 1536, *hb = A.r_lnhh_b + layer * 1536;
  const float *ig = A.r_lnih_g + 1536, *ib = A.r_lnih_b + 1536;
  for (int h = tid; h < 384; h += 256) {
    float gi, gf, gc, go;
    if (layer == 0) {
      gi = gih[h]; gf = gih[384 + h]; gc = gih[768 + h]; go = gih[1152 + h];
    } else {
      gi = ig[h] * (gih[h] - mu_ih) * inv_ih + ib[h];
      gf = ig[384 + h] * (gih[384 + h] - mu_ih) * inv_ih + ib[384 + h];
      gc = ig[768 + h] * (gih[768 + h] - mu_ih) * inv_ih + ib[768 + h];
      go = ig[1152 + h] * (gih[1152 + h] - mu_ih) * inv_ih + ib[1152 + h];
    }
    gi += hg[h] * (ghh[h] - mu_hh) * inv_hh + hb[h];
    gf += hg[384 + h] * (ghh[384 + h] - mu_hh) * inv_hh + hb[384 + h];
    gc += hg[768 + h] * (ghh[768 + h] - mu_hh) * inv_hh + hb[768 + h];
    go += hg[1152 + h] * (ghh[1152 + h] - mu_hh) * inv_hh + hb[1152 + h];
    float c = sigmoidf(gf) * selc[h] + sigmoidf(gi) * tanhf(gc);
    cnew[h] = c; ogat[h] = go;
  }
  __syncthreads();
  ps = 0.f;
  for (int h = tid; h < 384; h += 256) ps += cnew[h];
  float mu_c = blockSum(ps, red) * (1.f / 384.f);
  ps = 0.f;
  for (int h = tid; h < 384; h += 256) { float d = cnew[h] - mu_c; ps += d * d; }
  float inv_c = 1.f / (sqrtf(blockSum(ps, red) * (1.f / 383.f)) + 1e-6f);
  const float *lcg = A.r_lnc_g + layer * 384, *lcb = A.r_lnc_b + layer * 384;
  const int slot = t % 15;
  for (int h = tid; h < 384; h += 256) {
    float hn = sigmoidf(ogat[h]) * tanhf(lcg[h] * (cnew[h] - mu_c) * inv_c + lcb[h]);
    memh[slot * 384 + h] = hn;
    memc[slot * 384 + h] = cnew[h];
    if (layer == 0) {
      stx(ws + O_HNEW0 + (size_t)b * 384 + h, hn);
    } else {
      stx(ws + ((t & 1) ? O_HNEW1B : O_HNEW1A) + (size_t)b * 384 + h, hn);
      ws[O_OUTHS + tb * 768 + h] = hn;
    }
  }
}

__device__ void per_b_predict(int tau, int b, const ScanArgs& A, float* sm) {
  float* ws = A.ws;
  const int tid = threadIdx.x;
  const size_t tb = (size_t)tau * 32 + b;
  float* pmem = ws + O_PMEM + (size_t)b * 15 * 384;
  float* keyl = sm; float* logit = sm + 384; float* att = sm + 400;
  for (int h = tid; h < 384; h += 256)
    keyl[h] = ldx(ws + O_PKEYH + (size_t)b * 384 + h)
            + ldx(ws + O_PKEYMH + (size_t)(tau & 1) * 12288 + (size_t)b * 384 + h);
  __syncthreads();
  {
    int s = tid >> 4, l = tid & 15;
    if (s < 15) {
      const float* mh = pmem + ((tau + s) % 15) * 384;
      float p = 0.f;
      for (int k = l; k < 384; k += 16) p += mh[k] * keyl[k];
      p += __shfl_down(p, 8, 64); p += __shfl_down(p, 4, 64);
      p += __shfl_down(p, 2, 64); p += __shfl_down(p, 1, 64);
      if (l == 0) logit[s] = p * INV_SQRT_H;
    }
  }
  __syncthreads();
  if (tid == 0) {
    const float* mgp = ws + O_MGN + tb * 15;
    float m = logit[0];
    for (int i = 1; i < 15; ++i) m = fmaxf(m, logit[i]);
    float sum = 0.f;
    for (int i = 0; i < 15; ++i) { float e = expf(logit[i] - m) * mgp[i]; att[i] = e; sum += e; }
    float inv = 1.f / (sum + 1e-8f);
    for (int i = 0; i < 15; ++i) att[i] *= inv;
  }
  __syncthreads();
  float av[15]; int pidx[15];
#pragma unroll
  for (int i = 0; i < 15; ++i) { av[i] = att[i]; pidx[i] = (tau + i) % 15; }
  for (int h = tid; h < 384; h += 256) {
    float acc = 0.f;
#pragma unroll
    for (int i = 0; i < 15; ++i) acc += av[i] * pmem[pidx[i] * 384 + h];
    ws[O_OUTHS + tb * 768 + 384 + h] = acc;
  }
  __syncthreads();  // all pmem reads done before append overwrites oldest slot
  for (int h = tid; h < 384; h += 256)
    pmem[(tau % 15) * 384 + h] = ldx(ws + ((tau & 1) ? O_HNEW1B : O_HNEW1A) + (size_t)b * 384 + h);
}

// 2-phase pipelined scan:
//   E_s: wg0-31 L0(s) | wg32-63 L1(s-1) | wg64-95 PR(s-2)       (96 arrivals)
//   O_s: wg96-255 all GEMVs: G0(s) from h0(s), G1(s-1) from h1(s-1) (160 arr.)
__global__ __launch_bounds__(256) void k_scan(ScanArgs A) {
  __shared__ float sm[15488];           // per_b: <4672 | gemv: xs 12320 + red 3168
  float* ws = A.ws;
  unsigned* bar = (unsigned*)(ws + O_BAR);
  const int wg = blockIdx.x;
  const int tid = threadIdx.x;

  if (wg < 96) {
    const int g = wg >> 4;              // 6 groups of 16
    for (int s = 0; s < 194; ++s) {
      if (wg < 32) {
        if (s < 192) per_b_layer(0, s, wg, A, sm);
      } else if (wg < 64) {
        if (s >= 1 && s <= 192) per_b_layer(1, s - 1, wg - 32, A, sm);
      } else {
        if (s >= 2) per_b_predict(s - 2, wg - 64, A, sm);
      }
      __syncthreads();                  // drains stores (vmcnt0) before arrival
      if (tid == 0) {
        arrive2(bar, BO_GRP_E, BO_ROOT_E, BO_GEN_E, g, 6, (unsigned)s);
        if (s < 193) waitgen(bar, BO_GEN_O, (unsigned)s + 1);
      }
      __syncthreads();
    }
  } else {
    const int gwg = wg - 96;            // 0..159
    const int g = gwg >> 4;             // 10 groups of 16
    float* xs = sm;                     // 32 x 385 staged x (pad -> bank (b+k)%32)
    float* red = sm + 12320;
    const int b = tid & 31, cg = tid >> 5;
    const float* xp = xs + b * 385 + cg * 48;
    for (int s = 0; s < 193; ++s) {
      if (tid == 0) waitgen(bar, BO_GEN_E, (unsigned)s + 1);
      __syncthreads();
      const bool doG0 = (s < 192), doG1 = (s >= 1);
      const float* src1 = ws + (((s - 1) & 1) ? O_HNEW1B : O_HNEW1A);
      float xr[48];
      if (doG0) {
        for (int j = tid; j < 12288; j += 256) {
          int bb = j / 384, kk = j - bb * 384;
          xs[bb * 385 + kk] = ldx(ws + O_HNEW0 + j);
        }
        __syncthreads();
#pragma unroll
        for (int q = 0; q < 48; ++q) xr[q] = xp[q];
        float x1v[48];
        if (doG1) {                     // prefetch second x under G0 compute
#pragma unroll
          for (int q = 0; q < 48; ++q) x1v[q] = ldx(src1 + tid + q * 256);
        }
        __syncthreads();
        {
          GJob J0[4] = {
            { A.r_wih + 589824, 384, 0, A.r_bih + 1536, ws + O_IH1RAW, 1536, 1536 },
            { A.r_proj_w + 294912, 768, 0, A.r_proj_b + 384, ws + O_KEY1H, 384, 384 },
            { A.r_whh, 384, 0, nullptr, ws + O_P0 + (size_t)(s % 15) * 1536, 23040, 1536 },
            { A.r_proj_w, 768, 384, nullptr, ws + O_KEY0MH, 384, 384 },
          };
          gemv_half(J0, 3840, gwg, xr, red);
        }
        if (doG1) {
#pragma unroll
          for (int q = 0; q < 48; ++q) {
            int j = tid + q * 256;
            int bb = j / 384, kk = j - bb * 384;
            xs[bb * 385 + kk] = x1v[q];
          }
          __syncthreads();
#pragma unroll
          for (int q = 0; q < 48; ++q) xr[q] = xp[q];
        }
      } else {                          // s == 192: only G1
        for (int j = tid; j < 12288; j += 256) {
          int bb = j / 384, kk = j - bb * 384;
          xs[bb * 385 + kk] = ldx(src1 + j);
        }
        __syncthreads();
#pragma unroll
        for (int q = 0; q < 48; ++q) xr[q] = xp[q];
      }
      if (doG1) {
        GJob J1[4] = {
          { A.r_whh + 589824, 384, 0, nullptr, ws + O_P1 + (size_t)((s + 14) % 15) * 1536, 23040, 1536 },
          { A.r_proj_w + 294912, 768, 384, nullptr, ws + O_KEY1MH, 384, 384 },
          { A.p_proj_w, 768, 0, A.p_proj_b, ws + O_PKEYH, 384, 384 },
          { A.p_proj_w, 768, 384, nullptr, ws + O_PKEYMH + (size_t)(s & 1) * 12288, 384, 384 },
        };
        gemv_half(J1, 2688, gwg, xr, red);
      }
      __syncthreads();                  // drains stx before arrival
      if (tid == 0) arrive2(bar, BO_GRP_O, BO_ROOT_O, BO_GEN_O, g, 10, (unsigned)s);
    }
  }
}

// ---------------------------------------------------------------- launch
extern "C" void kernel_launch(void* const* d_in, const int* in_sizes, int n_in,
                              void* d_out, int out_size, void* d_ws, size_t ws_size,
                              hipStream_t stream) {
  const int* ids = (const int*)d_in[0];
  const float* emb_w = (const float*)d_in[1];
  const float* pconv1_w = (const float*)d_in[2];
  const float* pconv1_b = (const float*)d_in[3];
  const float* pbn_g = (const float*)d_in[4];
  const float* pbn_b = (const float*)d_in[5];
  const float* pconv2_w = (const float*)d_in[6];
  const float* pconv2_b = (const float*)d_in[7];
  const float* r_wih = (const float*)d_in[8];
  const float* r_bih = (const float*)d_in[9];
  const float* r_whh = (const float*)d_in[10];
  const float* r_bhh = (const float*)d_in[11];
  const float* r_lnih_g = (const float*)d_in[12];
  const float* r_lnih_b = (const float*)d_in[13];
  const float* r_lnhh_g = (const float*)d_in[14];
  const float* r_lnhh_b = (const float*)d_in[15];
  const float* r_lnc_g = (const float*)d_in[16];
  const float* r_lnc_b = (const float*)d_in[17];
  const float* r_proj_w = (const float*)d_in[18];
  const float* r_proj_b = (const float*)d_in[19];
  const float* p_proj_w = (const float*)d_in[20];
  const float* p_proj_b = (const float*)d_in[21];
  const float* p_ffd_w = (const float*)d_in[22];
  const float* p_ffd_b = (const float*)d_in[23];
  const float* p_bn_g = (const float*)d_in[24];
  const float* p_bn_b = (const float*)d_in[25];
  float* ws = (float*)d_ws;
  float* out = (float*)d_out;

  k_zero<<<1024, 256, 0, stream>>>(ws + O_MEMH0, (int)(O_WSEND - O_MEMH0));
  k_emb<<<4096, 256, 0, stream>>>(ids, emb_w, ws + O_EMB, out);
  k_conv<<<dim3(6, 96), 256, 0, stream>>>(ws + O_EMB, pconv1_w, pconv1_b, pbn_g, pbn_b, ws + O_H1);
  k_gate<<<6144, 256, 0, stream>>>(ws + O_H1, pconv2_w, pconv2_b, ws + O_GATEA, ws + O_GATEB);
  k_mg<<<24, 256, 0, stream>>>(ws + O_GATEA, ws + O_GATEB, ws + O_MG, ws + O_MGN);
  // precompute LN(e@Wih0+b) and key0_e = e@proj0_h + b for all t
  k_gemm<<<dim3(24, 96), 256, 0, stream>>>(ws + O_EMB, 384, r_wih, 384, r_bih,
                                           ws + O_IH0LN, 1536, 384, 0, nullptr, nullptr, nullptr);
  k_gemm<<<dim3(6, 96), 256, 0, stream>>>(ws + O_EMB, 384, r_proj_w, 768, r_proj_b,
                                          ws + O_KEY0E, 384, 384, 0, nullptr, nullptr, nullptr);
  k_ln_rows<<<6144, 256, 0, stream>>>(ws + O_IH0LN, r_lnih_g, r_lnih_b);
  ScanArgs SA{ws, r_whh, r_bhh, r_lnhh_g, r_lnhh_b, r_lnih_g, r_lnih_b,
              r_lnc_g, r_lnc_b, r_wih, r_bih, r_proj_w, r_proj_b, p_proj_w, p_proj_b};
  k_scan<<<256, 256, 0, stream>>>(SA);
  // head: y = tanh(BN(flat @ p_ffd^T + b)) -> out
  k_gemm<<<dim3(6, 96), 256, 0, stream>>>(ws + O_OUTHS, 768, p_ffd_w, 768, p_ffd_b,
                                          nullptr, 384, 768, 1, p_bn_g, p_bn_b, out);
}

// Round 2
// 14308.038 us; speedup vs baseline: 1.1333x; 1.1333x over previous
//
#include <hip/hip_runtime.h>

// PRPN eval forward for MI355X. All float inputs are FP32, ids int32.
// Output = [y (T*B*D) | mask (T*B)] fp32.
//
// R7 vs R5 (R6's serial 2-phase regressed and is abandoned):
//  - Keep R5's 3-phase overlapped scan (per-b work ∥ GEMV every phase).
//  - Per-b work split by wg class: wg0-31 L0, wg32-63 L1+PR, wg64-255 GEMV.
//    Each per-b wg owns its layer's P-cache as a PRIVATE MIRROR: GEMV writes
//    only the fresh slot to a small LLC staging buffer; the owner pulls it
//    (3 u64-ldx/thread) into the mirror and the 15-slot combine reads
//    normal cached loads (was 90 uncached LLC loads/thread/step).
//  - All cross-wg ldx/stx widened to 64-bit; pmem append now wg-local.
//  - Lane-parallel softmax (was tid0-serial); fused sum/sumsq blockSum2.
//  - L0 wgs prefetch IH0LN/KEY0E(t+1) during phase 3 (they were idle).

#define TT 192
#define TB 6144
#define NGV 192

constexpr size_t O_EMB    = 0;          // T*B*384 fp32
constexpr size_t O_IH0LN  = 2359296;    // T*B*1536 (raw then LN'd in place)
constexpr size_t O_KEY0E  = 11796480;   // T*B*384
constexpr size_t O_MG     = 14155776;   // T*B*15
constexpr size_t O_MGN    = 14247936;   // T*B*15
constexpr size_t O_H1     = 14340096;   // B*T x 384 conv acts (pre-scan only)
constexpr size_t O_P0S    = 14340096;   // staging: whh0@h0 fresh slot (32x1536), reuses dead O_H1
constexpr size_t O_P1S    = 14389248;   // staging: whh1@h1 fresh slot (32x1536)
constexpr size_t O_GATEA  = 16699392;   // B*T
constexpr size_t O_GATEB  = 16705536;   // B*T
constexpr size_t O_OUTHS  = 16711680;   // T*B x 768 (h | sel)
constexpr size_t O_MEMH0  = 21430272;   // state (zeroed): B x 15 x 384 each
constexpr size_t O_MEMC0  = 21614592;
constexpr size_t O_MEMH1  = 21798912;
constexpr size_t O_MEMC1  = 21983232;
constexpr size_t O_PMEM   = 22167552;
constexpr size_t O_P0     = 22351872;   // P0 mirror: B x 15 x 1536 (wg-private)
constexpr size_t O_P1     = 23089152;   // P1 mirror
constexpr size_t O_HNEW0  = 23826432;   // B x 384
constexpr size_t O_HNEW1  = 23838720;   // B x 384
constexpr size_t O_IH1RAW = 23851008;   // B x 1536
constexpr size_t O_KEY1H  = 23900160;
constexpr size_t O_KEY0MH = 23912448;
constexpr size_t O_KEY1MH = 23924736;
constexpr size_t O_PKEYH  = 23937024;
constexpr size_t O_PKEYMH = 23949312;   // 2 x B x 384 (ping-pong)
constexpr size_t O_BAR    = 23973888;   // barrier counters (544 u32, padded)
constexpr size_t O_WSEND  = 23974432;

__device__ __forceinline__ float sigmoidf(float x) { return 1.f / (1.f + expf(-x)); }

// LLC-coherent (bypass per-XCD L2) relaxed accessors for cross-wg exchange.
__device__ __forceinline__ float ldx(const float* p) {
  return __hip_atomic_load(p, __ATOMIC_RELAXED, __HIP_MEMORY_SCOPE_AGENT);
}
__device__ __forceinline__ void stx(float* p, float v) {
  __hip_atomic_store(p, v, __ATOMIC_RELAXED, __HIP_MEMORY_SCOPE_AGENT);
}
__device__ __forceinline__ float2 ldx2(const float* p) {
  unsigned long long v = __hip_atomic_load((const unsigned long long*)p,
                                           __ATOMIC_RELAXED, __HIP_MEMORY_SCOPE_AGENT);
  return __builtin_bit_cast(float2, v);
}
__device__ __forceinline__ void stx2(float* p, float2 v) {
  __hip_atomic_store((unsigned long long*)p, __builtin_bit_cast(unsigned long long, v),
                     __ATOMIC_RELAXED, __HIP_MEMORY_SCOPE_AGENT);
}
__device__ __forceinline__ unsigned ldu(const unsigned* p) {
  return __hip_atomic_load(p, __ATOMIC_RELAXED, __HIP_MEMORY_SCOPE_AGENT);
}

constexpr float BN_SC = 0.9999950000374997f;       // 1/sqrt(1+1e-5)
constexpr float INV_SQRT_H = 0.05103103630798288f; // 1/sqrt(384)

__device__ __forceinline__ float blockSum(float v, float* red) {
#pragma unroll
  for (int off = 32; off > 0; off >>= 1) v += __shfl_down(v, off, 64);
  __syncthreads();
  if ((threadIdx.x & 63) == 0) red[threadIdx.x >> 6] = v;
  __syncthreads();
  return red[0] + red[1] + red[2] + red[3];
}

// fused (sum, sumsq) reduction: one ladder instead of two.
__device__ __forceinline__ float2 blockSum2(float a, float b, float* red) {
#pragma unroll
  for (int off = 32; off > 0; off >>= 1) {
    a += __shfl_down(a, off, 64);
    b += __shfl_down(b, off, 64);
  }
  __syncthreads();
  if ((threadIdx.x & 63) == 0) { int w = threadIdx.x >> 6; red[2 * w] = a; red[2 * w + 1] = b; }
  __syncthreads();
  return make_float2(red[0] + red[2] + red[4] + red[6],
                     red[1] + red[3] + red[5] + red[7]);
}

// ---------------------------------------------------------------- k_zero
__global__ __launch_bounds__(256) void k_zero(float* p, int n) {
  int i = blockIdx.x * 256 + threadIdx.x;
  int stride = gridDim.x * 256;
  for (; i < n; i += stride) p[i] = 0.f;
}

// ---------------------------------------------------------------- k_emb (+mask)
__global__ __launch_bounds__(256) void k_emb(const int* ids, const float* emb_w,
                                             float* emb, float* out) {
  size_t idx = (size_t)blockIdx.x * 256 + threadIdx.x;
  size_t stride = (size_t)gridDim.x * 256;
  for (size_t i = idx; i < (size_t)TB * 384; i += stride) {
    size_t tb = i / 384, d = i - tb * 384;
    int id = ids[tb];
    emb[i] = emb_w[(size_t)id * 384 + d];
    if (i < TB) out[(size_t)TB * 384 + i] = (ids[i] != 0) ? 1.f : 0.f;
  }
}

// ---------------------------------------------------------------- k_conv (im2col GEMM)
__global__ __launch_bounds__(256) void k_conv(const float* emb, const float* W1, const float* cbias,
                                              const float* bng, const float* bnb, float* h1) {
  __shared__ float As[32][68];
  __shared__ float Bs[32][68];
  int n0 = blockIdx.x * 64, m0 = blockIdx.y * 64;
  int tid = threadIdx.x;
  float acc[4][4] = {};
  int mi = tid >> 3, kq = tid & 7;
  int ni = tid >> 2, kb = tid & 3;
  for (int kk = 0; kk < 2304; kk += 32) {
    int kc = kk / 384, dbase = kk - kc * 384;
    __syncthreads();
#pragma unroll
    for (int p = 0; p < 2; ++p) {
      int m = m0 + mi + 32 * p;
      int b = m / 192, t = m - b * 192;
      int tt = t + kc - 5;
      float4 v = {0.f, 0.f, 0.f, 0.f};
      if (tt >= 0) v = *(const float4*)(emb + ((size_t)tt * 32 + b) * 384 + dbase + kq * 4);
      As[kq * 4 + 0][mi + 32 * p] = v.x; As[kq * 4 + 1][mi + 32 * p] = v.y;
      As[kq * 4 + 2][mi + 32 * p] = v.z; As[kq * 4 + 3][mi + 32 * p] = v.w;
    }
#pragma unroll
    for (int i = 0; i < 8; ++i) {
      int d = dbase + kb * 8 + i;
      Bs[kb * 8 + i][ni] = W1[(size_t)(n0 + ni) * 2304 + d * 6 + kc];
    }
    __syncthreads();
    int ty = tid >> 4, tx = tid & 15;
#pragma unroll
    for (int k = 0; k < 32; ++k) {
      float4 a = *(const float4*)(&As[k][ty * 4]);
      float4 bv = *(const float4*)(&Bs[k][tx * 4]);
      acc[0][0] += a.x * bv.x; acc[0][1] += a.x * bv.y; acc[0][2] += a.x * bv.z; acc[0][3] += a.x * bv.w;
      acc[1][0] += a.y * bv.x; acc[1][1] += a.y * bv.y; acc[1][2] += a.y * bv.z; acc[1][3] += a.y * bv.w;
      acc[2][0] += a.z * bv.x; acc[2][1] += a.z * bv.y; acc[2][2] += a.z * bv.z; acc[2][3] += a.z * bv.w;
      acc[3][0] += a.w * bv.x; acc[3][1] += a.w * bv.y; acc[3][2] += a.w * bv.z; acc[3][3] += a.w * bv.w;
    }
  }
  int ty = tid >> 4, tx = tid & 15;
#pragma unroll
  for (int i = 0; i < 4; ++i) {
    int m = m0 + ty * 4 + i;
#pragma unroll
    for (int j = 0; j < 4; ++j) {
      int n = n0 + tx * 4 + j;
      float v = acc[i][j] + cbias[n];
      v = bng[n] * v * BN_SC + bnb[n];
      h1[(size_t)m * 384 + n] = fmaxf(v, 0.f);
    }
  }
}

// ---------------------------------------------------------------- k_gate
__global__ __launch_bounds__(256) void k_gate(const float* h1, const float* w2, const float* b2,
                                              float* gA, float* gB) {
  __shared__ float red[8];
  int bt = blockIdx.x, tid = threadIdx.x;
  float v0 = 0.f, v1 = 0.f;
  if (tid < 192) {
    v0 = h1[(size_t)bt * 384 + tid] * w2[tid];
    v1 = h1[(size_t)bt * 384 + 192 + tid] * w2[192 + tid];
  }
  float s0 = blockSum(v0, red);
  float s1 = blockSum(v1, red);
  if (tid == 0) {
    gA[bt] = 1.f / (1.f + expf(-(s0 + b2[0])));
    gB[bt] = 1.f / (1.f + expf(-(s1 + b2[1])));
  }
}

// ---------------------------------------------------------------- k_mg (hard gates + cumprod)
__global__ __launch_bounds__(256) void k_mg(const float* gA, const float* gB, float* mg, float* mgn) {
  int idx = blockIdx.x * 256 + threadIdx.x;
  if (idx >= TB) return;
  int t = idx >> 5, b = idx & 31;
  float g = gA[b * 192 + t], gn = gB[b * 192 + t];
  float p = 1.f, pn = 1.f;
  for (int k = 0; k < 15; ++k) {
    float ghat = (k <= t) ? gA[b * 192 + t - k] : 1e9f;
    float u = fminf(fmaxf((g - ghat) / 0.1f * 2.f + 1.f, -1.f), 1.f);
    float un = fminf(fmaxf((gn - ghat) / 0.1f * 2.f + 1.f, -1.f), 1.f);
    p *= (u + 1.f) * 0.5f;
    pn *= (un + 1.f) * 0.5f;
    mg[(size_t)idx * 15 + k] = p;
    mgn[(size_t)idx * 15 + k] = pn;
  }
}

// ---------------------------------------------------------------- k_gemm (generic)
__global__ __launch_bounds__(256) void k_gemm(const float* A, int lda, const float* W, int ldw,
                                              const float* bias, float* Cf, int ldc, int K, int mode,
                                              const float* bng, const float* bnb, float* Cb) {
  __shared__ float As[32][68];
  __shared__ float Bs[32][68];
  int n0 = blockIdx.x * 64, m0 = blockIdx.y * 64;
  int tid = threadIdx.x;
  float acc[4][4] = {};
  int mi = tid >> 3, kq = tid & 7;
  int ni = tid >> 2, kb = tid & 3;
  for (int kk = 0; kk < K; kk += 32) {
    __syncthreads();
#pragma unroll
    for (int p = 0; p < 2; ++p) {
      int m = m0 + mi + 32 * p;
      float4 v = *(const float4*)(A + (size_t)m * lda + kk + kq * 4);
      As[kq * 4 + 0][mi + 32 * p] = v.x; As[kq * 4 + 1][mi + 32 * p] = v.y;
      As[kq * 4 + 2][mi + 32 * p] = v.z; As[kq * 4 + 3][mi + 32 * p] = v.w;
    }
    {
      const float* wp = W + (size_t)(n0 + ni) * ldw + kk + kb * 8;
      float4 q0 = *(const float4*)(wp);
      float4 q1 = *(const float4*)(wp + 4);
      Bs[kb * 8 + 0][ni] = q0.x; Bs[kb * 8 + 1][ni] = q0.y;
      Bs[kb * 8 + 2][ni] = q0.z; Bs[kb * 8 + 3][ni] = q0.w;
      Bs[kb * 8 + 4][ni] = q1.x; Bs[kb * 8 + 5][ni] = q1.y;
      Bs[kb * 8 + 6][ni] = q1.z; Bs[kb * 8 + 7][ni] = q1.w;
    }
    __syncthreads();
    int ty = tid >> 4, tx = tid & 15;
#pragma unroll
    for (int k = 0; k < 32; ++k) {
      float4 a = *(const float4*)(&As[k][ty * 4]);
      float4 bv = *(const float4*)(&Bs[k][tx * 4]);
      acc[0][0] += a.x * bv.x; acc[0][1] += a.x * bv.y; acc[0][2] += a.x * bv.z; acc[0][3] += a.x * bv.w;
      acc[1][0] += a.y * bv.x; acc[1][1] += a.y * bv.y; acc[1][2] += a.y * bv.z; acc[1][3] += a.y * bv.w;
      acc[2][0] += a.z * bv.x; acc[2][1] += a.z * bv.y; acc[2][2] += a.z * bv.z; acc[2][3] += a.z * bv.w;
      acc[3][0] += a.w * bv.x; acc[3][1] += a.w * bv.y; acc[3][2] += a.w * bv.z; acc[3][3] += a.w * bv.w;
    }
  }
  int ty = tid >> 4, tx = tid & 15;
#pragma unroll
  for (int i = 0; i < 4; ++i) {
    int m = m0 + ty * 4 + i;
#pragma unroll
    for (int j = 0; j < 4; ++j) {
      int n = n0 + tx * 4 + j;
      float v = acc[i][j];
      if (bias) v += bias[n];
      if (mode == 0) Cf[(size_t)m * ldc + n] = v;
      else Cb[(size_t)m * ldc + n] = tanhf(bng[n] * v * BN_SC + bnb[n]);
    }
  }
}

// ---------------------------------------------------------------- k_ln_rows
__global__ __launch_bounds__(256) void k_ln_rows(float* X, const float* g, const float* bt) {
  __shared__ float red[8];
  float* x = X + (size_t)blockIdx.x * 1536;
  int tid = threadIdx.x;
  float ps = 0.f;
  for (int i = tid; i < 1536; i += 256) ps += x[i];
  float mu = blockSum(ps, red) * (1.f / 1536.f);
  ps = 0.f;
  for (int i = tid; i < 1536; i += 256) { float d = x[i] - mu; ps += d * d; }
  float inv = 1.f / (sqrtf(blockSum(ps, red) * (1.f / 1535.f)) + 1e-6f);
  for (int i = tid; i < 1536; i += 256) x[i] = g[i] * (x[i] - mu) * inv + bt[i];
}

// ---------------------------------------------------------------- scan kernel
struct ScanArgs {
  float* ws;
  const float *r_whh, *r_bhh, *r_lnhh_g, *r_lnhh_b, *r_lnih_g, *r_lnih_b;
  const float *r_lnc_g, *r_lnc_b, *r_wih, *r_bih, *r_proj_w, *r_proj_b;
  const float *p_proj_w, *p_proj_b;
};

struct GJob { const float* W; int ldw; int koff; const float* bias; float* dst; int rstride; int ncols; };

__device__ __forceinline__ void resolveJob(const GJob* J, int col, const float*& W, int& ldw, int& koff,
                                           const float*& bias, float*& dst, int& rstride, int& cc) {
  int c = col;
#pragma unroll
  for (int j = 0; j < 4; ++j) {
    if (c < J[j].ncols) {
      W = J[j].W; ldw = J[j].ldw; koff = J[j].koff; bias = J[j].bias;
      dst = J[j].dst; rstride = J[j].rstride; cc = c; return;
    }
    c -= J[j].ncols;
  }
  W = J[0].W; ldw = J[0].ldw; koff = J[0].koff; bias = J[0].bias;
  dst = J[0].dst; rstride = J[0].rstride; cc = 0;
}

// Hierarchical monotone-counter barrier: 16 groups x 16 wgs, counters on
// separate 64B lines, all relaxed (monotone -> no reset race).
__device__ void grid_barrier(unsigned* bar, int wg, unsigned k) {
  __syncthreads();
  if (threadIdx.x == 0) {
    const int g = wg >> 4;
    unsigned arr = __hip_atomic_fetch_add(bar + g * 16, 1u, __ATOMIC_RELAXED, __HIP_MEMORY_SCOPE_AGENT);
    if (arr == k * 16u + 15u) {                       // group leader
      unsigned ra = __hip_atomic_fetch_add(bar + 256, 1u, __ATOMIC_RELAXED, __HIP_MEMORY_SCOPE_AGENT);
      if (ra == k * 16u + 15u) {
        __hip_atomic_store(bar + 272, k + 1u, __ATOMIC_RELAXED, __HIP_MEMORY_SCOPE_AGENT);
      } else {
        while (ldu(bar + 272) < k + 1u) __builtin_amdgcn_s_sleep(2);
      }
      __hip_atomic_store(bar + 288 + g * 16, k + 1u, __ATOMIC_RELAXED, __HIP_MEMORY_SCOPE_AGENT);
    } else {
      while (ldu(bar + 288 + g * 16) < k + 1u) __builtin_amdgcn_s_sleep(4);
    }
  }
  __syncthreads();
}

// weight-shared GEMV phase: cols ragged-split over NGV wgs, K=384 split over 8
// thread-groups, partials in LDS (stride-33 pad). x staged to LDS via 64-bit
// LLC loads. Weights: plain loads (L2-resident, same cols every step).
__device__ void gemv_phase(const float* src, const GJob* J, int NC, int gwg,
                           float* xs /*32*385*/, float* red /*8*14*33*/) {
  const int tid = threadIdx.x;
  for (int j2 = tid; j2 < 6144; j2 += 256) {
    int j = j2 * 2;
    int bb = j / 384, kk = j - bb * 384;
    float2 v = ldx2(src + j);
    xs[bb * 385 + kk] = v.x; xs[bb * 385 + kk + 1] = v.y;
  }
  __syncthreads();
  const int b = tid & 31, cg = tid >> 5;
  const int c0 = (gwg * NC) / NGV, c1 = ((gwg + 1) * NC) / NGV;
  const int colsPer = c1 - c0;
  const int k0 = cg * 48;
  float xr[48];
  const float* xp = xs + b * 385 + k0;   // bank = (b + k) % 32: conflict-free
#pragma unroll
  for (int q = 0; q < 48; ++q) xr[q] = xp[q];
  for (int ci = 0; ci < colsPer; ++ci) {
    const float* W; int ldw, koff; const float* bias; float* dst; int rstride; int cc;
    resolveJob(J, c0 + ci, W, ldw, koff, bias, dst, rstride, cc);
    const float* wr = W + (size_t)cc * ldw + koff + k0;
    float a = 0.f;
#pragma unroll
    for (int q = 0; q < 12; ++q) {
      float4 w = *(const float4*)(wr + q * 4);
      a += w.x * xr[q * 4 + 0] + w.y * xr[q * 4 + 1]
         + w.z * xr[q * 4 + 2] + w.w * xr[q * 4 + 3];
    }
    red[(cg * colsPer + ci) * 33 + b] = a;
  }
  __syncthreads();
  const int pairs = colsPer * 32;
  for (int pi = tid; pi < pairs; pi += 256) {
    int bb = pi / colsPer, ci = pi - bb * colsPer;
    float s = 0.f;
#pragma unroll
    for (int g = 0; g < 8; ++g) s += red[(g * colsPer + ci) * 33 + bb];
    const float* W; int ldw, koff; const float* bias; float* dst; int rstride; int cc;
    resolveJob(J, c0 + ci, W, ldw, koff, bias, dst, rstride, cc);
    if (bias) s += bias[cc];
    stx(dst + (size_t)bb * rstride + cc, s);
  }
  __syncthreads();
}

// L0 idle-phase prefetch: pull IH0LN(t)/KEY0E(t) (precomputed) into LDS.
__device__ void preload_l0(int t, int b, const ScanArgs& A, float* sm) {
  float* ws = A.ws;
  const int tid = threadIdx.x;
  const size_t tb = (size_t)t * 32 + b;
  float* keyl = sm; float* gih = sm + 1984;
  for (int n = tid; n < 1536; n += 256) gih[n] = ws[O_IH0LN + tb * 1536 + n];
  if (tid < 192) {
    float2 v = *(const float2*)(ws + O_KEY0E + tb * 384 + 2 * tid);
    keyl[2 * tid] = v.x; keyl[2 * tid + 1] = v.y;
  }
}

// per-batch LSTM layer: attention (msoftmax, hard gate), P-mirror combine,
// LayerNorms, cell, LN(c), memory append.
// layer0: gih/keyl pre-loaded by preload_l0; layer1: pulled here via ldx2.
__device__ void per_b_layer(int layer, int t, int b, const ScanArgs& A, float* sm) {
  float* ws = A.ws;
  const int tid = threadIdx.x;
  const size_t tb = (size_t)t * 32 + b;
  float* memh = ws + (layer ? O_MEMH1 : O_MEMH0) + (size_t)b * 15 * 384;
  float* memc = ws + (layer ? O_MEMC1 : O_MEMC0) + (size_t)b * 15 * 384;
  float* mir  = ws + (layer ? O_P1 : O_P0) + (size_t)b * 23040;   // private mirror
  const float* stg = ws + (layer ? O_P1S : O_P0S) + (size_t)b * 1536;
  float* keyl = sm; float* logit = sm + 384; float* att = sm + 400; float* red = sm + 416;
  float* ghh = sm + 448; float* gih = sm + 1984; float* selc = sm + 3520;
  float* cnew = sm + 3904; float* ogat = sm + 4288;

  // pull fresh P slot (written by GEMV last phase) into the private mirror.
  const int pslot = (t + 14) % 15;
#pragma unroll
  for (int i = 0; i < 3; ++i) {
    int idx = tid + i * 256;
    float2 v = ldx2(stg + 2 * idx);
    *(float2*)(mir + (size_t)pslot * 1536 + 2 * idx) = v;
  }
  if (layer == 0) {
    if (tid < 192) {           // keyl preloaded with KEY0E; add mh part
      float2 c = ldx2(ws + O_KEY0MH + (size_t)b * 384 + 2 * tid);
      keyl[2 * tid] += c.x; keyl[2 * tid + 1] += c.y;
    }
  } else {
#pragma unroll
    for (int i = 0; i < 3; ++i) {
      int idx = tid + i * 256;
      float2 v = ldx2(ws + O_IH1RAW + (size_t)b * 1536 + 2 * idx);
      gih[2 * idx] = v.x; gih[2 * idx + 1] = v.y;
    }
    if (tid < 192) {
      float2 a = ldx2(ws + O_KEY1H + (size_t)b * 384 + 2 * tid);
      float2 c = ldx2(ws + O_KEY1MH + (size_t)b * 384 + 2 * tid);
      keyl[2 * tid] = a.x + c.x; keyl[2 * tid + 1] = a.y + c.y;
    }
  }
  float mgv = (tid < 15) ? ws[O_MG + tb * 15 + tid] : 0.f;
  __syncthreads();
  {
    int s = tid >> 4, l = tid & 15;
    if (s < 15) {
      const float* mh = memh + ((t + s) % 15) * 384;
      float p = 0.f;
      for (int k = l; k < 384; k += 16) p += mh[k] * keyl[k];
      p += __shfl_down(p, 8, 64); p += __shfl_down(p, 4, 64);
      p += __shfl_down(p, 2, 64); p += __shfl_down(p, 1, 64);
      if (l == 0) logit[s] = p * INV_SQRT_H;
    }
  }
  __syncthreads();
  if (tid < 64) {               // lane-parallel masked softmax (wave 0)
    float lg = (tid < 15) ? logit[tid] : -3.0e38f;
    lg = fmaxf(lg, __shfl_xor(lg, 8, 64));
    lg = fmaxf(lg, __shfl_xor(lg, 4, 64));
    lg = fmaxf(lg, __shfl_xor(lg, 2, 64));
    lg = fmaxf(lg, __shfl_xor(lg, 1, 64));
    float e = (tid < 15) ? expf(logit[tid] - lg) * mgv : 0.f;
    float ssum = e;
    ssum += __shfl_xor(ssum, 1, 64); ssum += __shfl_xor(ssum, 2, 64);
    ssum += __shfl_xor(ssum, 4, 64); ssum += __shfl_xor(ssum, 8, 64);
    if (tid < 15) att[tid] = e / (ssum + 1e-8f);
  }
  __syncthreads();
  float av[15]; int pidx[15];
#pragma unroll
  for (int i = 0; i < 15; ++i) { av[i] = att[i]; pidx[i] = (t + i) % 15; }
  const float* bhh = A.r_bhh + layer * 1536;
  for (int n = tid; n < 1536; n += 256) {
    float acc = bhh[n];
#pragma unroll
    for (int i = 0; i < 15; ++i) acc += av[i] * mir[(size_t)pidx[i] * 1536 + n];
    ghh[n] = acc;
  }
  for (int h = tid; h < 384; h += 256) {
    float acc = 0.f;
#pragma unroll
    for (int i = 0; i < 15; ++i) acc += av[i] * memc[pidx[i] * 384 + h];
    selc[h] = acc;
  }
  __syncthreads();
  float s1 = 0.f, s2 = 0.f;
  for (int n = tid; n < 1536; n += 256) { float v = ghh[n]; s1 += v; s2 += v * v; }
  float2 rhh = blockSum2(s1, s2, red);
  float mu_hh = rhh.x * (1.f / 1536.f);
  float inv_hh = 1.f / (sqrtf(fmaxf(rhh.y - rhh.x * mu_hh, 0.f) * (1.f / 1535.f)) + 1e-6f);
  float mu_ih = 0.f, inv_ih = 0.f;
  if (layer) {
    s1 = 0.f; s2 = 0.f;
    for (int n = tid; n < 1536; n += 256) { float v = gih[n]; s1 += v; s2 += v * v; }
    float2 rih = blockSum2(s1, s2, red);
    mu_ih = rih.x * (1.f / 1536.f);
    inv_ih = 1.f / (sqrtf(fmaxf(rih.y - rih.x * mu_ih, 0.f) * (1.f / 1535.f)) + 1e-6f);
  }
  const float *hg = A.r_lnhh_g + layer * 1536, *hb = A.r_lnhh_b + layer * 1536;
  const float *ig = A.r_lnih_g + 1536, *ib = A.r_lnih_b + 1536;
  for (int h = tid; h < 384; h += 256) {
    float gi, gf, gc, go;
    if (layer == 0) {
      gi = gih[h]; gf = gih[384 + h]; gc = gih[768 + h]; go = gih[1152 + h];
    } else {
      gi = ig[h] * (gih[h] - mu_ih) * inv_ih + ib[h];
      gf = ig[384 + h] * (gih[384 + h] - mu_ih) * inv_ih + ib[384 + h];
      gc = ig[768 + h] * (gih[768 + h] - mu_ih) * inv_ih + ib[768 + h];
      go = ig[1152 + h] * (gih[1152 + h] - mu_ih) * inv_ih + ib[1152 + h];
    }
    gi += hg[h] * (ghh[h] - mu_hh) * inv_hh + hb[h];
    gf += hg[384 + h] * (ghh[384 + h] - mu_hh) * inv_hh + hb[384 + h];
    gc += hg[768 + h] * (ghh[768 + h] - mu_hh) * inv_hh + hb[768 + h];
    go += hg[1152 + h] * (ghh[1152 + h] - mu_hh) * inv_hh + hb[1152 + h];
    float c = sigmoidf(gf) * selc[h] + sigmoidf(gi) * tanhf(gc);
    cnew[h] = c; ogat[h] = go;
  }
  __syncthreads();
  s1 = 0.f; s2 = 0.f;
  for (int h = tid; h < 384; h += 256) { float v = cnew[h]; s1 += v; s2 += v * v; }
  float2 rc = blockSum2(s1, s2, red);
  float mu_c = rc.x * (1.f / 384.f);
  float inv_c = 1.f / (sqrtf(fmaxf(rc.y - rc.x * mu_c, 0.f) * (1.f / 383.f)) + 1e-6f);
  const float *lcg = A.r_lnc_g + layer * 384, *lcb = A.r_lnc_b + layer * 384;
  const int slot = t % 15;
  if (tid < 192) {
    int h0 = 2 * tid, h1 = h0 + 1;
    float c0 = cnew[h0], c1 = cnew[h1];
    float hn0 = sigmoidf(ogat[h0]) * tanhf(lcg[h0] * (c0 - mu_c) * inv_c + lcb[h0]);
    float hn1 = sigmoidf(ogat[h1]) * tanhf(lcg[h1] * (c1 - mu_c) * inv_c + lcb[h1]);
    *(float2*)(memh + slot * 384 + h0) = make_float2(hn0, hn1);
    *(float2*)(memc + slot * 384 + h0) = make_float2(c0, c1);
    stx2(ws + (layer ? O_HNEW1 : O_HNEW0) + (size_t)b * 384 + h0, make_float2(hn0, hn1));
    if (layer) *(float2*)(ws + O_OUTHS + tb * 768 + h0) = make_float2(hn0, hn1);
  }
}

__device__ void per_b_predict(int tau, int b, const ScanArgs& A, float* sm) {
  float* ws = A.ws;
  const int tid = threadIdx.x;
  const size_t tb = (size_t)tau * 32 + b;
  float* pmem = ws + O_PMEM + (size_t)b * 15 * 384;     // wg-private (same wg as L1)
  const float* memh1 = ws + O_MEMH1 + (size_t)b * 15 * 384;
  float* keyl = sm; float* logit = sm + 384; float* att = sm + 400;
  if (tid < 192) {
    float2 a = ldx2(ws + O_PKEYH + (size_t)b * 384 + 2 * tid);
    float2 c = ldx2(ws + O_PKEYMH + (size_t)(tau & 1) * 12288 + (size_t)b * 384 + 2 * tid);
    keyl[2 * tid] = a.x + c.x; keyl[2 * tid + 1] = a.y + c.y;
  }
  float mgv = (tid < 15) ? ws[O_MGN + tb * 15 + tid] : 0.f;
  __syncthreads();
  {
    int s = tid >> 4, l = tid & 15;
    if (s < 15) {
      const float* mh = pmem + ((tau + s) % 15) * 384;
      float p = 0.f;
      for (int k = l; k < 384; k += 16) p += mh[k] * keyl[k];
      p += __shfl_down(p, 8, 64); p += __shfl_down(p, 4, 64);
      p += __shfl_down(p, 2, 64); p += __shfl_down(p, 1, 64);
      if (l == 0) logit[s] = p * INV_SQRT_H;
    }
  }
  __syncthreads();
  if (tid < 64) {
    float lg = (tid < 15) ? logit[tid] : -3.0e38f;
    lg = fmaxf(lg, __shfl_xor(lg, 8, 64));
    lg = fmaxf(lg, __shfl_xor(lg, 4, 64));
    lg = fmaxf(lg, __shfl_xor(lg, 2, 64));
    lg = fmaxf(lg, __shfl_xor(lg, 1, 64));
    float e = (tid < 15) ? expf(logit[tid] - lg) * mgv : 0.f;
    float ssum = e;
    ssum += __shfl_xor(ssum, 1, 64); ssum += __shfl_xor(ssum, 2, 64);
    ssum += __shfl_xor(ssum, 4, 64); ssum += __shfl_xor(ssum, 8, 64);
    if (tid < 15) att[tid] = e / (ssum + 1e-8f);
  }
  __syncthreads();
  float av[15]; int pidx[15];
#pragma unroll
  for (int i = 0; i < 15; ++i) { av[i] = att[i]; pidx[i] = (tau + i) % 15; }
  for (int h = tid; h < 384; h += 256) {
    float acc = 0.f;
#pragma unroll
    for (int i = 0; i < 15; ++i) acc += av[i] * pmem[pidx[i] * 384 + h];
    ws[O_OUTHS + tb * 768 + 384 + h] = acc;
  }
  __syncthreads();  // all pmem reads done before append overwrites oldest slot
  if (tid < 192) {  // append h1(tau) from own memh1 (same wg wrote it)
    const int slot = tau % 15;
    *(float2*)(pmem + slot * 384 + 2 * tid) =
        *(const float2*)(memh1 + slot * 384 + 2 * tid);
  }
}

// 3-phase overlapped scan (R5 skeleton, per-b classes split):
//  P1: [wg0-31]  L0(t)     | [wg64+] GEMV(h1(t-1)): whh1->P1S, proj1mh->KEY1MH,
//                                     pproj->PKEYH, pproj_m->PKEYMH[par]
//  P2: [wg32-63] PR(t-1)   | [wg64+] GEMV(h0(t)):   wih1->IH1RAW, proj1h->KEY1H
//  P3: [wg32-63] L1(t)     | [wg64+] GEMV(h0(t)):   whh0->P0S, proj0mh->KEY0MH
//      [wg0-31] prefetch IH0LN/KEY0E(t+1)
__global__ __launch_bounds__(256) void k_scan(ScanArgs A) {
  __shared__ float sm[16032];           // per_b: <4672 | gemv: xs 12320 + red 3696
  float* ws = A.ws;
  unsigned* bar = (unsigned*)(ws + O_BAR);
  const int wg = blockIdx.x;
  float* xs = sm;
  float* red = sm + 12320;
  unsigned bk = 0;
  if (wg < 32) preload_l0(0, wg, A, sm);
  for (int t = 0; t <= TT; ++t) {
    // ---- Phase 1 ----
    if (wg < 32) {
      if (t < TT) per_b_layer(0, t, wg, A, sm);
    } else if (wg >= 64) {
      GJob J[4] = {
        { A.r_whh + 589824, 384, 0, nullptr, ws + O_P1S, 1536, 1536 },
        { A.r_proj_w + 294912, 768, 384, nullptr, ws + O_KEY1MH, 384, 384 },
        { A.p_proj_w, 768, 0, A.p_proj_b, ws + O_PKEYH, 384, 384 },
        { A.p_proj_w, 768, 384, nullptr, ws + O_PKEYMH + (size_t)(t & 1) * 12288, 384, 384 },
      };
      gemv_phase(ws + O_HNEW1, J, 2688, wg - 64, xs, red);
    }
    grid_barrier(bar, wg, bk); ++bk;
    // ---- Phase 2 ----
    if (wg >= 32 && wg < 64) {
      if (t >= 1) per_b_predict(t - 1, wg - 32, A, sm);
    } else if (wg >= 64 && t < TT) {
      GJob J[4] = {
        { A.r_wih + 589824, 384, 0, A.r_bih + 1536, ws + O_IH1RAW, 1536, 1536 },
        { A.r_proj_w + 294912, 768, 0, A.r_proj_b + 384, ws + O_KEY1H, 384, 384 },
        { nullptr, 0, 0, nullptr, nullptr, 0, 0 },
        { nullptr, 0, 0, nullptr, nullptr, 0, 0 },
      };
      gemv_phase(ws + O_HNEW0, J, 1920, wg - 64, xs, red);
    }
    if (t == TT) break;
    grid_barrier(bar, wg, bk); ++bk;
    // ---- Phase 3 ----
    if (wg >= 32 && wg < 64) {
      per_b_layer(1, t, wg - 32, A, sm);
    } else if (wg < 32) {
      if (t + 1 < TT) preload_l0(t + 1, wg, A, sm);
    } else {
      GJob J[4] = {
        { A.r_whh, 384, 0, nullptr, ws + O_P0S, 1536, 1536 },
        { A.r_proj_w, 768, 384, nullptr, ws + O_KEY0MH, 384, 384 },
        { nullptr, 0, 0, nullptr, nullptr, 0, 0 },
        { nullptr, 0, 0, nullptr, nullptr, 0, 0 },
      };
      gemv_phase(ws + O_HNEW0, J, 1920, wg - 64, xs, red);
    }
    grid_barrier(bar, wg, bk); ++bk;
  }
}

// ---------------------------------------------------------------- launch
extern "C" void kernel_launch(void* const* d_in, const int* in_sizes, int n_in,
                              void* d_out, int out_size, void* d_ws, size_t ws_size,
                              hipStream_t stream) {
  const int* ids = (const int*)d_in[0];
  const float* emb_w = (const float*)d_in[1];
  const float* pconv1_w = (const float*)d_in[2];
  const float* pconv1_b = (const float*)d_in[3];
  const float* pbn_g = (const float*)d_in[4];
  const float* pbn_b = (const float*)d_in[5];
  const float* pconv2_w = (const float*)d_in[6];
  const float* pconv2_b = (const float*)d_in[7];
  const float* r_wih = (const float*)d_in[8];
  const float* r_bih = (const float*)d_in[9];
  const float* r_whh = (const float*)d_in[10];
  const float* r_bhh = (const float*)d_in[11];
  const float* r_lnih_g = (const float*)d_in[12];
  const float* r_lnih_b = (const float*)d_in[13];
  const float* r_lnhh_g = (const float*)d_in[14];
  const float* r_lnhh_b = (const float*)d_in[15];
  const float* r_lnc_g = (const float*)d_in[16];
  const float* r_lnc_b = (const float*)d_in[17];
  const float* r_proj_w = (const float*)d_in[18];
  const float* r_proj_b = (const float*)d_in[19];
  const float* p_proj_w = (const float*)d_in[20];
  const float* p_proj_b = (const float*)d_in[21];
  const float* p_ffd_w = (const float*)d_in[22];
  const float* p_ffd_b = (const float*)d_in[23];
  const float* p_bn_g = (const float*)d_in[24];
  const float* p_bn_b = (const float*)d_in[25];
  float* ws = (float*)d_ws;
  float* out = (float*)d_out;

  k_zero<<<1024, 256, 0, stream>>>(ws + O_MEMH0, (int)(O_WSEND - O_MEMH0));
  k_emb<<<4096, 256, 0, stream>>>(ids, emb_w, ws + O_EMB, out);
  k_conv<<<dim3(6, 96), 256, 0, stream>>>(ws + O_EMB, pconv1_w, pconv1_b, pbn_g, pbn_b, ws + O_H1);
  k_gate<<<6144, 256, 0, stream>>>(ws + O_H1, pconv2_w, pconv2_b, ws + O_GATEA, ws + O_GATEB);
  k_mg<<<24, 256, 0, stream>>>(ws + O_GATEA, ws + O_GATEB, ws + O_MG, ws + O_MGN);
  // staging buffers live in the (now dead) conv-activation region: zero after k_gate.
  k_zero<<<96, 256, 0, stream>>>(ws + O_P0S, 98304);
  // precompute LN(e@Wih0+b) and key0_e = e@proj0_h + b for all t
  k_gemm<<<dim3(24, 96), 256, 0, stream>>>(ws + O_EMB, 384, r_wih, 384, r_bih,
                                           ws + O_IH0LN, 1536, 384, 0, nullptr, nullptr, nullptr);
  k_gemm<<<dim3(6, 96), 256, 0, stream>>>(ws + O_EMB, 384, r_proj_w, 768, r_proj_b,
                                          ws + O_KEY0E, 384, 384, 0, nullptr, nullptr, nullptr);
  k_ln_rows<<<6144, 256, 0, stream>>>(ws + O_IH0LN, r_lnih_g, r_lnih_b);
  ScanArgs SA{ws, r_whh, r_bhh, r_lnhh_g, r_lnhh_b, r_lnih_g, r_lnih_b,
              r_lnc_g, r_lnc_b, r_wih, r_bih, r_proj_w, r_proj_b, p_proj_w, p_proj_b};
  k_scan<<<256, 256, 0, stream>>>(SA);
  // head: y = tanh(BN(flat @ p_ffd^T + b)) -> out
  k_gemm<<<dim3(6, 96), 256, 0, stream>>>(ws + O_OUTHS, 768, p_ffd_w, 768, p_ffd_b,
                                          nullptr, 384, 768, 1, p_bn_g, p_bn_b, out);
}

// Round 3
// 13153.221 us; speedup vs baseline: 1.2328x; 1.0878x over previous
//
#include <hip/hip_runtime.h>

// PRPN eval forward for MI355X. All float inputs are FP32, ids int32.
// Output = [y (T*B*D) | mask (T*B)] fp32.
//
// R8: decoupled dual-pipeline scan (replaces the 3-global-phase structure).
//  - Domain A (wg0-127): 32 L0 wgs + 96 G0 GEMV wgs, private 2-gate/step loop.
//    G0(h0(t)): wih1->IH1RAW[par], proj1h->KEY1H[par], whh0->P0S, proj0mh->KEY0MH.
//  - Domain B (wg128-223): 32 L1 wgs + 64 G1 GEMV wgs, private 2-gate/step loop.
//    G1(h1(t)): whh1->P1S, proj1mh->KEY1MH, pproj->PKEYH[par], pprojm->PKEYMH[par].
//  - PR (wg224-255): free-running consumer, polls domB gen, bumps PRCNT.
//  - Cross-pipe: L1(t) waits domA gen>=2t+2; G0(t) waits domB gen>=2t-3 (L1(t-2)
//    consumed IH1RAW parity); G1(t) waits PRCNT>=32t (PR(t-1) consumed PKEY parity).
//  - The three per-b latency chains (L0, L1, PR) now run CONCURRENTLY; step time
//    = max(pipe periods) instead of their sum.
//  - Per-b internals carried from R7 (mirror P-cache, wide LLC ops, lane softmax,
//    fused sum/sumsq reductions, L0 preload of IH0LN/KEY0E in the G0 window).

#define TT 192
#define TB 6144

constexpr size_t O_EMB    = 0;          // T*B*384 fp32
constexpr size_t O_IH0LN  = 2359296;    // T*B*1536 (raw then LN'd in place)
constexpr size_t O_KEY0E  = 11796480;   // T*B*384
constexpr size_t O_MG     = 14155776;   // T*B*15
constexpr size_t O_MGN    = 14247936;   // T*B*15
// ---- dead conv-activation region reused for scan exchange buffers ----
constexpr size_t O_H1     = 14340096;   // B*T x 384 conv acts (pre-scan only)
constexpr size_t O_P0S    = 14340096;   // 32x1536 staging whh0@h0
constexpr size_t O_P1S    = 14389248;   // 32x1536 staging whh1@h1
constexpr size_t O_IH1RAW = 14438400;   // [2] x 32x1536 (parity)
constexpr size_t O_KEY1H  = 14536704;   // [2] x 32x384
constexpr size_t O_KEY0MH = 14561280;   // 32x384
constexpr size_t O_KEY1MH = 14573568;   // 32x384
constexpr size_t O_PKEYH  = 14585856;   // [2] x 32x384
constexpr size_t O_PKEYMH = 14610432;   // [2] x 32x384
constexpr size_t O_HNEW0  = 14635008;   // 32x384
constexpr size_t O_HNEW1  = 14647296;   // [2] x 32x384
constexpr size_t O_BAR    = 14671872;   // counters (1024 floats)
constexpr size_t O_DEADEND= 14672896;
// ---------------------------------------------------------------------
constexpr size_t O_GATEA  = 16699392;   // B*T
constexpr size_t O_GATEB  = 16705536;   // B*T
constexpr size_t O_OUTHS  = 16711680;   // T*B x 768 (h | sel)
constexpr size_t O_MEMH0  = 21430272;   // state (zeroed): B x 15 x 384 each
constexpr size_t O_MEMC0  = 21614592;
constexpr size_t O_MEMH1  = 21798912;
constexpr size_t O_MEMC1  = 21983232;
constexpr size_t O_PMEM   = 22167552;
constexpr size_t O_P0     = 22351872;   // P0 mirror: B x 15 x 1536 (wg-private)
constexpr size_t O_P1     = 23089152;   // P1 mirror
constexpr size_t O_STATEEND = 23826432;

// BAR u32 layout
#define A_GRP   0     // 8 lines (g*16)
#define A_ROOT  128
#define A_GEN   144
#define B_GRP   160   // 6 lines (160+g*16)
#define B_ROOT  272
#define B_GEN   288
#define PRCNT   304

__device__ __forceinline__ float sigmoidf(float x) { return 1.f / (1.f + expf(-x)); }

__device__ __forceinline__ float ldx(const float* p) {
  return __hip_atomic_load(p, __ATOMIC_RELAXED, __HIP_MEMORY_SCOPE_AGENT);
}
__device__ __forceinline__ void stx(float* p, float v) {
  __hip_atomic_store(p, v, __ATOMIC_RELAXED, __HIP_MEMORY_SCOPE_AGENT);
}
__device__ __forceinline__ float2 ldx2(const float* p) {
  unsigned long long v = __hip_atomic_load((const unsigned long long*)p,
                                           __ATOMIC_RELAXED, __HIP_MEMORY_SCOPE_AGENT);
  return __builtin_bit_cast(float2, v);
}
__device__ __forceinline__ void stx2(float* p, float2 v) {
  __hip_atomic_store((unsigned long long*)p, __builtin_bit_cast(unsigned long long, v),
                     __ATOMIC_RELAXED, __HIP_MEMORY_SCOPE_AGENT);
}
__device__ __forceinline__ unsigned ldu(const unsigned* p) {
  return __hip_atomic_load(p, __ATOMIC_RELAXED, __HIP_MEMORY_SCOPE_AGENT);
}

constexpr float BN_SC = 0.9999950000374997f;       // 1/sqrt(1+1e-5)
constexpr float INV_SQRT_H = 0.05103103630798288f; // 1/sqrt(384)

__device__ __forceinline__ float blockSum(float v, float* red) {
#pragma unroll
  for (int off = 32; off > 0; off >>= 1) v += __shfl_down(v, off, 64);
  __syncthreads();
  if ((threadIdx.x & 63) == 0) red[threadIdx.x >> 6] = v;
  __syncthreads();
  return red[0] + red[1] + red[2] + red[3];
}

__device__ __forceinline__ float2 blockSum2(float a, float b, float* red) {
#pragma unroll
  for (int off = 32; off > 0; off >>= 1) {
    a += __shfl_down(a, off, 64);
    b += __shfl_down(b, off, 64);
  }
  __syncthreads();
  if ((threadIdx.x & 63) == 0) { int w = threadIdx.x >> 6; red[2 * w] = a; red[2 * w + 1] = b; }
  __syncthreads();
  return make_float2(red[0] + red[2] + red[4] + red[6],
                     red[1] + red[3] + red[5] + red[7]);
}

// ---------------------------------------------------------------- k_zero
__global__ __launch_bounds__(256) void k_zero(float* p, int n) {
  int i = blockIdx.x * 256 + threadIdx.x;
  int stride = gridDim.x * 256;
  for (; i < n; i += stride) p[i] = 0.f;
}

// ---------------------------------------------------------------- k_emb (+mask)
__global__ __launch_bounds__(256) void k_emb(const int* ids, const float* emb_w,
                                             float* emb, float* out) {
  size_t idx = (size_t)blockIdx.x * 256 + threadIdx.x;
  size_t stride = (size_t)gridDim.x * 256;
  for (size_t i = idx; i < (size_t)TB * 384; i += stride) {
    size_t tb = i / 384, d = i - tb * 384;
    int id = ids[tb];
    emb[i] = emb_w[(size_t)id * 384 + d];
    if (i < TB) out[(size_t)TB * 384 + i] = (ids[i] != 0) ? 1.f : 0.f;
  }
}

// ---------------------------------------------------------------- k_conv (im2col GEMM)
__global__ __launch_bounds__(256) void k_conv(const float* emb, const float* W1, const float* cbias,
                                              const float* bng, const float* bnb, float* h1) {
  __shared__ float As[32][68];
  __shared__ float Bs[32][68];
  int n0 = blockIdx.x * 64, m0 = blockIdx.y * 64;
  int tid = threadIdx.x;
  float acc[4][4] = {};
  int mi = tid >> 3, kq = tid & 7;
  int ni = tid >> 2, kb = tid & 3;
  for (int kk = 0; kk < 2304; kk += 32) {
    int kc = kk / 384, dbase = kk - kc * 384;
    __syncthreads();
#pragma unroll
    for (int p = 0; p < 2; ++p) {
      int m = m0 + mi + 32 * p;
      int b = m / 192, t = m - b * 192;
      int tt = t + kc - 5;
      float4 v = {0.f, 0.f, 0.f, 0.f};
      if (tt >= 0) v = *(const float4*)(emb + ((size_t)tt * 32 + b) * 384 + dbase + kq * 4);
      As[kq * 4 + 0][mi + 32 * p] = v.x; As[kq * 4 + 1][mi + 32 * p] = v.y;
      As[kq * 4 + 2][mi + 32 * p] = v.z; As[kq * 4 + 3][mi + 32 * p] = v.w;
    }
#pragma unroll
    for (int i = 0; i < 8; ++i) {
      int d = dbase + kb * 8 + i;
      Bs[kb * 8 + i][ni] = W1[(size_t)(n0 + ni) * 2304 + d * 6 + kc];
    }
    __syncthreads();
    int ty = tid >> 4, tx = tid & 15;
#pragma unroll
    for (int k = 0; k < 32; ++k) {
      float4 a = *(const float4*)(&As[k][ty * 4]);
      float4 bv = *(const float4*)(&Bs[k][tx * 4]);
      acc[0][0] += a.x * bv.x; acc[0][1] += a.x * bv.y; acc[0][2] += a.x * bv.z; acc[0][3] += a.x * bv.w;
      acc[1][0] += a.y * bv.x; acc[1][1] += a.y * bv.y; acc[1][2] += a.y * bv.z; acc[1][3] += a.y * bv.w;
      acc[2][0] += a.z * bv.x; acc[2][1] += a.z * bv.y; acc[2][2] += a.z * bv.z; acc[2][3] += a.z * bv.w;
      acc[3][0] += a.w * bv.x; acc[3][1] += a.w * bv.y; acc[3][2] += a.w * bv.z; acc[3][3] += a.w * bv.w;
    }
  }
  int ty = tid >> 4, tx = tid & 15;
#pragma unroll
  for (int i = 0; i < 4; ++i) {
    int m = m0 + ty * 4 + i;
#pragma unroll
    for (int j = 0; j < 4; ++j) {
      int n = n0 + tx * 4 + j;
      float v = acc[i][j] + cbias[n];
      v = bng[n] * v * BN_SC + bnb[n];
      h1[(size_t)m * 384 + n] = fmaxf(v, 0.f);
    }
  }
}

// ---------------------------------------------------------------- k_gate
__global__ __launch_bounds__(256) void k_gate(const float* h1, const float* w2, const float* b2,
                                              float* gA, float* gB) {
  __shared__ float red[8];
  int bt = blockIdx.x, tid = threadIdx.x;
  float v0 = 0.f, v1 = 0.f;
  if (tid < 192) {
    v0 = h1[(size_t)bt * 384 + tid] * w2[tid];
    v1 = h1[(size_t)bt * 384 + 192 + tid] * w2[192 + tid];
  }
  float s0 = blockSum(v0, red);
  float s1 = blockSum(v1, red);
  if (tid == 0) {
    gA[bt] = 1.f / (1.f + expf(-(s0 + b2[0])));
    gB[bt] = 1.f / (1.f + expf(-(s1 + b2[1])));
  }
}

// ---------------------------------------------------------------- k_mg (hard gates + cumprod)
__global__ __launch_bounds__(256) void k_mg(const float* gA, const float* gB, float* mg, float* mgn) {
  int idx = blockIdx.x * 256 + threadIdx.x;
  if (idx >= TB) return;
  int t = idx >> 5, b = idx & 31;
  float g = gA[b * 192 + t], gn = gB[b * 192 + t];
  float p = 1.f, pn = 1.f;
  for (int k = 0; k < 15; ++k) {
    float ghat = (k <= t) ? gA[b * 192 + t - k] : 1e9f;
    float u = fminf(fmaxf((g - ghat) / 0.1f * 2.f + 1.f, -1.f), 1.f);
    float un = fminf(fmaxf((gn - ghat) / 0.1f * 2.f + 1.f, -1.f), 1.f);
    p *= (u + 1.f) * 0.5f;
    pn *= (un + 1.f) * 0.5f;
    mg[(size_t)idx * 15 + k] = p;
    mgn[(size_t)idx * 15 + k] = pn;
  }
}

// ---------------------------------------------------------------- k_gemm (generic)
__global__ __launch_bounds__(256) void k_gemm(const float* A, int lda, const float* W, int ldw,
                                              const float* bias, float* Cf, int ldc, int K, int mode,
                                              const float* bng, const float* bnb, float* Cb) {
  __shared__ float As[32][68];
  __shared__ float Bs[32][68];
  int n0 = blockIdx.x * 64, m0 = blockIdx.y * 64;
  int tid = threadIdx.x;
  float acc[4][4] = {};
  int mi = tid >> 3, kq = tid & 7;
  int ni = tid >> 2, kb = tid & 3;
  for (int kk = 0; kk < K; kk += 32) {
    __syncthreads();
#pragma unroll
    for (int p = 0; p < 2; ++p) {
      int m = m0 + mi + 32 * p;
      float4 v = *(const float4*)(A + (size_t)m * lda + kk + kq * 4);
      As[kq * 4 + 0][mi + 32 * p] = v.x; As[kq * 4 + 1][mi + 32 * p] = v.y;
      As[kq * 4 + 2][mi + 32 * p] = v.z; As[kq * 4 + 3][mi + 32 * p] = v.w;
    }
    {
      const float* wp = W + (size_t)(n0 + ni) * ldw + kk + kb * 8;
      float4 q0 = *(const float4*)(wp);
      float4 q1 = *(const float4*)(wp + 4);
      Bs[kb * 8 + 0][ni] = q0.x; Bs[kb * 8 + 1][ni] = q0.y;
      Bs[kb * 8 + 2][ni] = q0.z; Bs[kb * 8 + 3][ni] = q0.w;
      Bs[kb * 8 + 4][ni] = q1.x; Bs[kb * 8 + 5][ni] = q1.y;
      Bs[kb * 8 + 6][ni] = q1.z; Bs[kb * 8 + 7][ni] = q1.w;
    }
    __syncthreads();
    int ty = tid >> 4, tx = tid & 15;
#pragma unroll
    for (int k = 0; k < 32; ++k) {
      float4 a = *(const float4*)(&As[k][ty * 4]);
      float4 bv = *(const float4*)(&Bs[k][tx * 4]);
      acc[0][0] += a.x * bv.x; acc[0][1] += a.x * bv.y; acc[0][2] += a.x * bv.z; acc[0][3] += a.x * bv.w;
      acc[1][0] += a.y * bv.x; acc[1][1] += a.y * bv.y; acc[1][2] += a.y * bv.z; acc[1][3] += a.y * bv.w;
      acc[2][0] += a.z * bv.x; acc[2][1] += a.z * bv.y; acc[2][2] += a.z * bv.z; acc[2][3] += a.z * bv.w;
      acc[3][0] += a.w * bv.x; acc[3][1] += a.w * bv.y; acc[3][2] += a.w * bv.z; acc[3][3] += a.w * bv.w;
    }
  }
  int ty = tid >> 4, tx = tid & 15;
#pragma unroll
  for (int i = 0; i < 4; ++i) {
    int m = m0 + ty * 4 + i;
#pragma unroll
    for (int j = 0; j < 4; ++j) {
      int n = n0 + tx * 4 + j;
      float v = acc[i][j];
      if (bias) v += bias[n];
      if (mode == 0) Cf[(size_t)m * ldc + n] = v;
      else Cb[(size_t)m * ldc + n] = tanhf(bng[n] * v * BN_SC + bnb[n]);
    }
  }
}

// ---------------------------------------------------------------- k_ln_rows
__global__ __launch_bounds__(256) void k_ln_rows(float* X, const float* g, const float* bt) {
  __shared__ float red[8];
  float* x = X + (size_t)blockIdx.x * 1536;
  int tid = threadIdx.x;
  float ps = 0.f;
  for (int i = tid; i < 1536; i += 256) ps += x[i];
  float mu = blockSum(ps, red) * (1.f / 1536.f);
  ps = 0.f;
  for (int i = tid; i < 1536; i += 256) { float d = x[i] - mu; ps += d * d; }
  float inv = 1.f / (sqrtf(blockSum(ps, red) * (1.f / 1535.f)) + 1e-6f);
  for (int i = tid; i < 1536; i += 256) x[i] = g[i] * (x[i] - mu) * inv + bt[i];
}

// ---------------------------------------------------------------- scan kernel
struct ScanArgs {
  float* ws;
  const float *r_whh, *r_bhh, *r_lnhh_g, *r_lnhh_b, *r_lnih_g, *r_lnih_b;
  const float *r_lnc_g, *r_lnc_b, *r_wih, *r_bih, *r_proj_w, *r_proj_b;
  const float *p_proj_w, *p_proj_b;
};

struct GJob { const float* W; int ldw; int koff; const float* bias; float* dst; int rstride; int ncols; };

__device__ __forceinline__ void resolveJob(const GJob* J, int col, const float*& W, int& ldw, int& koff,
                                           const float*& bias, float*& dst, int& rstride, int& cc) {
  int c = col;
#pragma unroll
  for (int j = 0; j < 4; ++j) {
    if (c < J[j].ncols) {
      W = J[j].W; ldw = J[j].ldw; koff = J[j].koff; bias = J[j].bias;
      dst = J[j].dst; rstride = J[j].rstride; cc = c; return;
    }
    c -= J[j].ncols;
  }
  W = J[0].W; ldw = J[0].ldw; koff = J[0].koff; bias = J[0].bias;
  dst = J[0].dst; rstride = J[0].rstride; cc = 0;
}

// per-domain gate: monotone 2-level counters (group line + root), followers
// poll the root generation directly. tid0 only.
__device__ __forceinline__ void gate_arrive(unsigned* bar, int grpBase, int rootOff,
                                            int genOff, int g, int ngroups, unsigned k) {
  unsigned a = __hip_atomic_fetch_add(bar + grpBase + g * 16, 1u, __ATOMIC_RELAXED, __HIP_MEMORY_SCOPE_AGENT);
  if (a == k * 16u + 15u) {
    unsigned r = __hip_atomic_fetch_add(bar + rootOff, 1u, __ATOMIC_RELAXED, __HIP_MEMORY_SCOPE_AGENT);
    if (r == k * (unsigned)ngroups + (unsigned)(ngroups - 1))
      __hip_atomic_store(bar + genOff, k + 1u, __ATOMIC_RELAXED, __HIP_MEMORY_SCOPE_AGENT);
  }
}
__device__ __forceinline__ void waitgen(const unsigned* bar, int genOff, unsigned tgt) {
  while (ldu(bar + genOff) < tgt) __builtin_amdgcn_s_sleep(2);
}

// stage x (32x384) into LDS [32][385] via 64-bit LLC loads
__device__ __forceinline__ void stage_x(const float* src, float* xs) {
  const int tid = threadIdx.x;
  for (int j2 = tid; j2 < 6144; j2 += 256) {
    int j = j2 * 2;
    int bb = j / 384, kk = j - bb * 384;
    float2 v = ldx2(src + j);
    xs[bb * 385 + kk] = v.x; xs[bb * 385 + kk + 1] = v.y;
  }
}

// GEMV: ncols cols of the job set, K=384 over 8 thread-groups of 48,
// shfl-pair -> 4 LDS partial rows (stride 33), chunked by 21 cols.
__device__ void gemv_run(const GJob* J, int cbase, int ncols, const float* xs, float* red) {
  const int tid = threadIdx.x;
  const int b = tid & 31, cg = tid >> 5;
  float xr[48];
  const float* xp = xs + b * 385 + cg * 48;
#pragma unroll
  for (int q = 0; q < 48; ++q) xr[q] = xp[q];
  for (int ch = 0; ch < ncols; ch += 21) {
    const int nch = min(21, ncols - ch);
    for (int ci = 0; ci < nch; ++ci) {
      const float* W; int ldw, koff; const float* bias; float* dst; int rstride; int cc;
      resolveJob(J, cbase + ch + ci, W, ldw, koff, bias, dst, rstride, cc);
      const float* wr = W + (size_t)cc * ldw + koff + cg * 48;
      float a = 0.f;
#pragma unroll
      for (int q = 0; q < 12; ++q) {
        float4 w = *(const float4*)(wr + q * 4);
        a += w.x * xr[q * 4 + 0] + w.y * xr[q * 4 + 1]
           + w.z * xr[q * 4 + 2] + w.w * xr[q * 4 + 3];
      }
      a += __shfl_down(a, 32, 64);
      if ((cg & 1) == 0) red[((cg >> 1) * nch + ci) * 33 + b] = a;
    }
    __syncthreads();
    const int pairs = nch * 32;
    for (int pi = tid; pi < pairs; pi += 256) {
      int bb = pi / nch, ci = pi - bb * nch;
      float s = red[(0 * nch + ci) * 33 + bb] + red[(1 * nch + ci) * 33 + bb]
              + red[(2 * nch + ci) * 33 + bb] + red[(3 * nch + ci) * 33 + bb];
      const float* W; int ldw, koff; const float* bias; float* dst; int rstride; int cc;
      resolveJob(J, cbase + ch + ci, W, ldw, koff, bias, dst, rstride, cc);
      if (bias) s += bias[cc];
      stx(dst + (size_t)bb * rstride + cc, s);
    }
    __syncthreads();
  }
}

// L0 preload: IH0LN(t)/KEY0E(t) (precomputed) into LDS (runs in the G0 window).
__device__ void preload_l0(int t, int b, const ScanArgs& A, float* sm) {
  float* ws = A.ws;
  const int tid = threadIdx.x;
  const size_t tb = (size_t)t * 32 + b;
  float* keyl = sm; float* gih = sm + 1984;
  for (int n = tid; n < 1536; n += 256) gih[n] = ws[O_IH0LN + tb * 1536 + n];
  if (tid < 192) {
    float2 v = *(const float2*)(ws + O_KEY0E + tb * 384 + 2 * tid);
    keyl[2 * tid] = v.x; keyl[2 * tid + 1] = v.y;
  }
}

// sm layout for per-b: keyl 0..384 | logit 384 | att 400 | red 416 |
// ghh 448..1984 | gih 1984..3520 | selc 3520 | cnew 3904 | ogat 4288..4672
__device__ void per_b_attn(int t, const float* memh, float* sm, const float* mgp) {
  const int tid = threadIdx.x;
  float* keyl = sm; float* logit = sm + 384; float* att = sm + 400;
  float mgv = (tid < 15) ? mgp[tid] : 0.f;
  __syncthreads();
  {
    int s = tid >> 4, l = tid & 15;
    if (s < 15) {
      const float* mh = memh + ((t + s) % 15) * 384;
      float p = 0.f;
      for (int k = l; k < 384; k += 16) p += mh[k] * keyl[k];
      p += __shfl_down(p, 8, 64); p += __shfl_down(p, 4, 64);
      p += __shfl_down(p, 2, 64); p += __shfl_down(p, 1, 64);
      if (l == 0) logit[s] = p * INV_SQRT_H;
    }
  }
  __syncthreads();
  if (tid < 64) {
    float lg = (tid < 15) ? logit[tid] : -3.0e38f;
    lg = fmaxf(lg, __shfl_xor(lg, 8, 64));
    lg = fmaxf(lg, __shfl_xor(lg, 4, 64));
    lg = fmaxf(lg, __shfl_xor(lg, 2, 64));
    lg = fmaxf(lg, __shfl_xor(lg, 1, 64));
    float e = (tid < 15) ? expf(logit[tid] - lg) * mgv : 0.f;
    float ssum = e;
    ssum += __shfl_xor(ssum, 1, 64); ssum += __shfl_xor(ssum, 2, 64);
    ssum += __shfl_xor(ssum, 4, 64); ssum += __shfl_xor(ssum, 8, 64);
    if (tid < 15) att[tid] = e / (ssum + 1e-8f);
  }
  __syncthreads();
}

// shared tail of both layers: combine, LNs, cell, LN(c), writes.
__device__ void per_b_tail(int layer, int t, int b, const ScanArgs& A, float* sm,
                           float* memh, float* memc, const float* mir,
                           float mu_ih, float inv_ih) {
  float* ws = A.ws;
  const int tid = threadIdx.x;
  const size_t tb = (size_t)t * 32 + b;
  float* att = sm + 400; float* red = sm + 416;
  float* ghh = sm + 448; float* gih = sm + 1984; float* selc = sm + 3520;
  float* cnew = sm + 3904; float* ogat = sm + 4288;
  float av[15]; int pidx[15];
#pragma unroll
  for (int i = 0; i < 15; ++i) { av[i] = att[i]; pidx[i] = (t + i) % 15; }
  const float* bhh = A.r_bhh + layer * 1536;
  for (int n = tid; n < 1536; n += 256) {
    float acc = bhh[n];
#pragma unroll
    for (int i = 0; i < 15; ++i) acc += av[i] * mir[(size_t)pidx[i] * 1536 + n];
    ghh[n] = acc;
  }
  for (int h = tid; h < 384; h += 256) {
    float acc = 0.f;
#pragma unroll
    for (int i = 0; i < 15; ++i) acc += av[i] * memc[pidx[i] * 384 + h];
    selc[h] = acc;
  }
  __syncthreads();
  float s1 = 0.f, s2 = 0.f;
  for (int n = tid; n < 1536; n += 256) { float v = ghh[n]; s1 += v; s2 += v * v; }
  float2 rhh = blockSum2(s1, s2, red);
  float mu_hh = rhh.x * (1.f / 1536.f);
  float inv_hh = 1.f / (sqrtf(fmaxf(rhh.y - rhh.x * mu_hh, 0.f) * (1.f / 1535.f)) + 1e-6f);
  const float *hg = A.r_lnhh_g + layer * 1536, *hb = A.r_lnhh_b + layer * 1536;
  const float *ig = A.r_lnih_g + 1536, *ib = A.r_lnih_b + 1536;
  for (int h = tid; h < 384; h += 256) {
    float gi, gf, gc, go;
    if (layer == 0) {
      gi = gih[h]; gf = gih[384 + h]; gc = gih[768 + h]; go = gih[1152 + h];
    } else {
      gi = ig[h] * (gih[h] - mu_ih) * inv_ih + ib[h];
      gf = ig[384 + h] * (gih[384 + h] - mu_ih) * inv_ih + ib[384 + h];
      gc = ig[768 + h] * (gih[768 + h] - mu_ih) * inv_ih + ib[768 + h];
      go = ig[1152 + h] * (gih[1152 + h] - mu_ih) * inv_ih + ib[1152 + h];
    }
    gi += hg[h] * (ghh[h] - mu_hh) * inv_hh + hb[h];
    gf += hg[384 + h] * (ghh[384 + h] - mu_hh) * inv_hh + hb[384 + h];
    gc += hg[768 + h] * (ghh[768 + h] - mu_hh) * inv_hh + hb[768 + h];
    go += hg[1152 + h] * (ghh[1152 + h] - mu_hh) * inv_hh + hb[1152 + h];
    float c = sigmoidf(gf) * selc[h] + sigmoidf(gi) * tanhf(gc);
    cnew[h] = c; ogat[h] = go;
  }
  __syncthreads();
  s1 = 0.f; s2 = 0.f;
  for (int h = tid; h < 384; h += 256) { float v = cnew[h]; s1 += v; s2 += v * v; }
  float2 rc = blockSum2(s1, s2, red);
  float mu_c = rc.x * (1.f / 384.f);
  float inv_c = 1.f / (sqrtf(fmaxf(rc.y - rc.x * mu_c, 0.f) * (1.f / 383.f)) + 1e-6f);
  const float *lcg = A.r_lnc_g + layer * 384, *lcb = A.r_lnc_b + layer * 384;
  const int slot = t % 15;
  if (tid < 192) {
    int h0 = 2 * tid, h1 = h0 + 1;
    float c0 = cnew[h0], c1 = cnew[h1];
    float hn0 = sigmoidf(ogat[h0]) * tanhf(lcg[h0] * (c0 - mu_c) * inv_c + lcb[h0]);
    float hn1 = sigmoidf(ogat[h1]) * tanhf(lcg[h1] * (c1 - mu_c) * inv_c + lcb[h1]);
    *(float2*)(memh + slot * 384 + h0) = make_float2(hn0, hn1);
    *(float2*)(memc + slot * 384 + h0) = make_float2(c0, c1);
    if (layer == 0) {
      stx2(ws + O_HNEW0 + (size_t)b * 384 + h0, make_float2(hn0, hn1));
    } else {
      stx2(ws + O_HNEW1 + (size_t)(t & 1) * 12288 + (size_t)b * 384 + h0, make_float2(hn0, hn1));
      *(float2*)(ws + O_OUTHS + tb * 768 + h0) = make_float2(hn0, hn1);
    }
  }
}

__device__ void per_b_layer0(int t, int b, const ScanArgs& A, float* sm) {
  float* ws = A.ws;
  const int tid = threadIdx.x;
  const size_t tb = (size_t)t * 32 + b;
  float* memh = ws + O_MEMH0 + (size_t)b * 5760;
  float* memc = ws + O_MEMC0 + (size_t)b * 5760;
  float* mir  = ws + O_P0 + (size_t)b * 23040;
  const float* stg = ws + O_P0S + (size_t)b * 1536;
  float* keyl = sm;
  const int pslot = (t + 14) % 15;
#pragma unroll
  for (int i = 0; i < 3; ++i) {
    int idx = tid + i * 256;
    float2 v = ldx2(stg + 2 * idx);
    *(float2*)(mir + (size_t)pslot * 1536 + 2 * idx) = v;
  }
  if (tid < 192) {             // keyl preloaded with KEY0E(t); add mh part
    float2 c = ldx2(ws + O_KEY0MH + (size_t)b * 384 + 2 * tid);
    keyl[2 * tid] += c.x; keyl[2 * tid + 1] += c.y;
  }
  per_b_attn(t, memh, sm, ws + O_MG + tb * 15);
  per_b_tail(0, t, b, A, sm, memh, memc, mir, 0.f, 0.f);
}

__device__ void per_b_layer1(int t, int b, const ScanArgs& A, float* sm) {
  float* ws = A.ws;
  const int tid = threadIdx.x;
  const size_t tb = (size_t)t * 32 + b;
  const size_t par = (size_t)(t & 1);
  float* memh = ws + O_MEMH1 + (size_t)b * 5760;
  float* memc = ws + O_MEMC1 + (size_t)b * 5760;
  float* mir  = ws + O_P1 + (size_t)b * 23040;
  const float* stg = ws + O_P1S + (size_t)b * 1536;
  float* keyl = sm; float* red = sm + 416; float* gih = sm + 1984;
  const int pslot = (t + 14) % 15;
#pragma unroll
  for (int i = 0; i < 3; ++i) {
    int idx = tid + i * 256;
    float2 v = ldx2(stg + 2 * idx);
    *(float2*)(mir + (size_t)pslot * 1536 + 2 * idx) = v;
  }
#pragma unroll
  for (int i = 0; i < 3; ++i) {
    int idx = tid + i * 256;
    float2 v = ldx2(ws + O_IH1RAW + par * 49152 + (size_t)b * 1536 + 2 * idx);
    gih[2 * idx] = v.x; gih[2 * idx + 1] = v.y;
  }
  if (tid < 192) {
    float2 a = ldx2(ws + O_KEY1H + par * 12288 + (size_t)b * 384 + 2 * tid);
    float2 c = ldx2(ws + O_KEY1MH + (size_t)b * 384 + 2 * tid);
    keyl[2 * tid] = a.x + c.x; keyl[2 * tid + 1] = a.y + c.y;
  }
  per_b_attn(t, memh, sm, ws + O_MG + tb * 15);
  float s1 = 0.f, s2 = 0.f;
  for (int n = tid; n < 1536; n += 256) { float v = gih[n]; s1 += v; s2 += v * v; }
  float2 rih = blockSum2(s1, s2, red);
  float mu_ih = rih.x * (1.f / 1536.f);
  float inv_ih = 1.f / (sqrtf(fmaxf(rih.y - rih.x * mu_ih, 0.f) * (1.f / 1535.f)) + 1e-6f);
  per_b_tail(1, t, b, A, sm, memh, memc, mir, mu_ih, inv_ih);
}

__device__ void per_b_predict(int t, int b, const ScanArgs& A, float* sm) {
  float* ws = A.ws;
  const int tid = threadIdx.x;
  const size_t tb = (size_t)t * 32 + b;
  float* pmem = ws + O_PMEM + (size_t)b * 5760;
  float* keyl = sm; float* logit = sm + 384; float* att = sm + 400;
  if (tid < 192) {
    float2 a = ldx2(ws + O_PKEYH + (size_t)(t & 1) * 12288 + (size_t)b * 384 + 2 * tid);
    float2 c = ldx2(ws + O_PKEYMH + (size_t)((t + 1) & 1) * 12288 + (size_t)b * 384 + 2 * tid);
    keyl[2 * tid] = a.x + c.x; keyl[2 * tid + 1] = a.y + c.y;
  }
  float mgv = (tid < 15) ? ws[O_MGN + tb * 15 + tid] : 0.f;
  __syncthreads();
  {
    int s = tid >> 4, l = tid & 15;
    if (s < 15) {
      const float* mh = pmem + ((t + s) % 15) * 384;
      float p = 0.f;
      for (int k = l; k < 384; k += 16) p += mh[k] * keyl[k];
      p += __shfl_down(p, 8, 64); p += __shfl_down(p, 4, 64);
      p += __shfl_down(p, 2, 64); p += __shfl_down(p, 1, 64);
      if (l == 0) logit[s] = p * INV_SQRT_H;
    }
  }
  __syncthreads();
  if (tid < 64) {
    float lg = (tid < 15) ? logit[tid] : -3.0e38f;
    lg = fmaxf(lg, __shfl_xor(lg, 8, 64));
    lg = fmaxf(lg, __shfl_xor(lg, 4, 64));
    lg = fmaxf(lg, __shfl_xor(lg, 2, 64));
    lg = fmaxf(lg, __shfl_xor(lg, 1, 64));
    float e = (tid < 15) ? expf(logit[tid] - lg) * mgv : 0.f;
    float ssum = e;
    ssum += __shfl_xor(ssum, 1, 64); ssum += __shfl_xor(ssum, 2, 64);
    ssum += __shfl_xor(ssum, 4, 64); ssum += __shfl_xor(ssum, 8, 64);
    if (tid < 15) att[tid] = e / (ssum + 1e-8f);
  }
  __syncthreads();
  float av[15]; int pidx[15];
#pragma unroll
  for (int i = 0; i < 15; ++i) { av[i] = att[i]; pidx[i] = (t + i) % 15; }
  for (int h = tid; h < 384; h += 256) {
    float acc = 0.f;
#pragma unroll
    for (int i = 0; i < 15; ++i) acc += av[i] * pmem[pidx[i] * 384 + h];
    ws[O_OUTHS + tb * 768 + 384 + h] = acc;
  }
  __syncthreads();  // all pmem reads done before append overwrites oldest slot
  if (tid < 192) {  // append h1(t) from HNEW1[t&1]
    const int slot = t % 15;
    float2 v = ldx2(ws + O_HNEW1 + (size_t)(t & 1) * 12288 + (size_t)b * 384 + 2 * tid);
    *(float2*)(pmem + slot * 384 + 2 * tid) = v;
  }
}

// ---- decoupled dual-pipeline scan ----
// domain A (wg0-127, 8 grps): L0 wgs (0-31), G0 wgs (32-127). 2 gates/step.
// domain B (wg128-223, 6 grps): L1 wgs (128-159), G1 wgs (160-223). 2 gates/step.
// PR (wg224-255): free-running, polls B_GEN, bumps PRCNT.
__global__ __launch_bounds__(256) void k_scan(ScanArgs A) {
  __shared__ float sm[15104];           // per-b <4672 | gemv xs 12320 + red 2772
  float* ws = A.ws;
  unsigned* bar = (unsigned*)(ws + O_BAR);
  const int wg = blockIdx.x;
  const int tid = threadIdx.x;

  if (wg < 32) {                        // ================= L0 (domain A)
    const int b = wg, g = wg >> 4;
    preload_l0(0, b, A, sm);
    __syncthreads();
    unsigned ka = 0;
    for (int t = 0; t < 192; ++t, ka += 2) {
      per_b_layer0(t, b, A, sm);
      __syncthreads();                  // drain stores before arrival
      if (tid == 0) gate_arrive(bar, A_GRP, A_ROOT, A_GEN, g, 8, ka);
      if (t + 1 < 192) preload_l0(t + 1, b, A, sm);   // in the G0 window
      __syncthreads();
      if (tid == 0) {
        waitgen(bar, A_GEN, ka + 1);
        gate_arrive(bar, A_GRP, A_ROOT, A_GEN, g, 8, ka + 1);
        waitgen(bar, A_GEN, ka + 2);    // G0(t) done -> P0S/KEY0MH ready
      }
      __syncthreads();
    }
  } else if (wg < 128) {                // ================= G0 (domain A)
    const int g = wg >> 4;
    const int cbase = (wg - 32) * 40;   // 3840 cols over 96 wgs
    float* xs = sm; float* red = sm + 12320;
    unsigned ka = 0;
    for (int t = 0; t < 192; ++t, ka += 2) {
      if (tid == 0) {
        gate_arrive(bar, A_GRP, A_ROOT, A_GEN, g, 8, ka);
        waitgen(bar, A_GEN, ka + 1);    // h0(t) ready
      }
      __syncthreads();
      stage_x(ws + O_HNEW0, xs);
      if (tid == 0 && t >= 2) waitgen(bar, B_GEN, 2u * t - 3u);  // L1(t-2) done
      __syncthreads();
      {
        const size_t par = (size_t)(t & 1);
        GJob J[4] = {
          { A.r_wih + 589824, 384, 0, A.r_bih + 1536, ws + O_IH1RAW + par * 49152, 1536, 1536 },
          { A.r_proj_w + 294912, 768, 0, A.r_proj_b + 384, ws + O_KEY1H + par * 12288, 384, 384 },
          { A.r_whh, 384, 0, nullptr, ws + O_P0S, 1536, 1536 },
          { A.r_proj_w, 768, 384, nullptr, ws + O_KEY0MH, 384, 384 },
        };
        gemv_run(J, cbase, 40, xs, red);
      }
      if (tid == 0) {
        gate_arrive(bar, A_GRP, A_ROOT, A_GEN, g, 8, ka + 1);
        waitgen(bar, A_GEN, ka + 2);
      }
      __syncthreads();
    }
  } else if (wg < 160) {                // ================= L1 (domain B)
    const int b = wg - 128, g = (wg - 128) >> 4;
    unsigned kb = 0;
    for (int t = 0; t < 192; ++t, kb += 2) {
      if (tid == 0) waitgen(bar, A_GEN, 2u * t + 2u);   // G0(t) done
      __syncthreads();
      per_b_layer1(t, b, A, sm);
      __syncthreads();
      if (tid == 0) {
        gate_arrive(bar, B_GRP, B_ROOT, B_GEN, g, 6, kb);
        waitgen(bar, B_GEN, kb + 1);
        gate_arrive(bar, B_GRP, B_ROOT, B_GEN, g, 6, kb + 1);
        waitgen(bar, B_GEN, kb + 2);    // G1(t) done -> P1S/KEY1MH ready
      }
      __syncthreads();
    }
  } else if (wg < 224) {                // ================= G1 (domain B)
    const int g = (wg - 128) >> 4;
    const int cbase = (wg - 160) * 42;  // 2688 cols over 64 wgs
    float* xs = sm; float* red = sm + 12320;
    unsigned kb = 0;
    for (int t = 0; t < 192; ++t, kb += 2) {
      if (tid == 0) {
        gate_arrive(bar, B_GRP, B_ROOT, B_GEN, g, 6, kb);
        waitgen(bar, B_GEN, kb + 1);    // h1(t) ready
      }
      __syncthreads();
      stage_x(ws + O_HNEW1 + (size_t)(t & 1) * 12288, xs);
      if (tid == 0) {                   // PR(t-1) consumed PKEY parity
        while (ldu(bar + PRCNT) < 32u * (unsigned)t) __builtin_amdgcn_s_sleep(2);
      }
      __syncthreads();
      {
        const size_t par = (size_t)(t & 1);
        GJob J[4] = {
          { A.r_whh + 589824, 384, 0, nullptr, ws + O_P1S, 1536, 1536 },
          { A.r_proj_w + 294912, 768, 384, nullptr, ws + O_KEY1MH, 384, 384 },
          { A.p_proj_w, 768, 0, A.p_proj_b, ws + O_PKEYH + par * 12288, 384, 384 },
          { A.p_proj_w, 768, 384, nullptr, ws + O_PKEYMH + par * 12288, 384, 384 },
        };
        gemv_run(J, cbase, 42, xs, red);
      }
      if (tid == 0) {
        gate_arrive(bar, B_GRP, B_ROOT, B_GEN, g, 6, kb + 1);
        waitgen(bar, B_GEN, kb + 2);
      }
      __syncthreads();
    }
  } else {                              // ================= PR (free-running)
    const int b = wg - 224;
    for (int t = 0; t < 192; ++t) {
      if (tid == 0) waitgen(bar, B_GEN, 2u * t + 2u);   // G1(t) done
      __syncthreads();
      per_b_predict(t, b, A, sm);
      __syncthreads();
      if (tid == 0)
        __hip_atomic_fetch_add(bar + PRCNT, 1u, __ATOMIC_RELAXED, __HIP_MEMORY_SCOPE_AGENT);
    }
  }
}

// ---------------------------------------------------------------- launch
extern "C" void kernel_launch(void* const* d_in, const int* in_sizes, int n_in,
                              void* d_out, int out_size, void* d_ws, size_t ws_size,
                              hipStream_t stream) {
  const int* ids = (const int*)d_in[0];
  const float* emb_w = (const float*)d_in[1];
  const float* pconv1_w = (const float*)d_in[2];
  const float* pconv1_b = (const float*)d_in[3];
  const float* pbn_g = (const float*)d_in[4];
  const float* pbn_b = (const float*)d_in[5];
  const float* pconv2_w = (const float*)d_in[6];
  const float* pconv2_b = (const float*)d_in[7];
  const float* r_wih = (const float*)d_in[8];
  const float* r_bih = (const float*)d_in[9];
  const float* r_whh = (const float*)d_in[10];
  const float* r_bhh = (const float*)d_in[11];
  const float* r_lnih_g = (const float*)d_in[12];
  const float* r_lnih_b = (const float*)d_in[13];
  const float* r_lnhh_g = (const float*)d_in[14];
  const float* r_lnhh_b = (const float*)d_in[15];
  const float* r_lnc_g = (const float*)d_in[16];
  const float* r_lnc_b = (const float*)d_in[17];
  const float* r_proj_w = (const float*)d_in[18];
  const float* r_proj_b = (const float*)d_in[19];
  const float* p_proj_w = (const float*)d_in[20];
  const float* p_proj_b = (const float*)d_in[21];
  const float* p_ffd_w = (const float*)d_in[22];
  const float* p_ffd_b = (const float*)d_in[23];
  const float* p_bn_g = (const float*)d_in[24];
  const float* p_bn_b = (const float*)d_in[25];
  float* ws = (float*)d_ws;
  float* out = (float*)d_out;

  k_zero<<<1024, 256, 0, stream>>>(ws + O_MEMH0, (int)(O_STATEEND - O_MEMH0));
  k_emb<<<4096, 256, 0, stream>>>(ids, emb_w, ws + O_EMB, out);
  k_conv<<<dim3(6, 96), 256, 0, stream>>>(ws + O_EMB, pconv1_w, pconv1_b, pbn_g, pbn_b, ws + O_H1);
  k_gate<<<6144, 256, 0, stream>>>(ws + O_H1, pconv2_w, pconv2_b, ws + O_GATEA, ws + O_GATEB);
  k_mg<<<24, 256, 0, stream>>>(ws + O_GATEA, ws + O_GATEB, ws + O_MG, ws + O_MGN);
  // exchange buffers + counters live in the (now dead) conv-activation region
  k_zero<<<326, 256, 0, stream>>>(ws + O_P0S, (int)(O_DEADEND - O_P0S));
  // precompute LN(e@Wih0+b) and key0_e = e@proj0_h + b for all t
  k_gemm<<<dim3(24, 96), 256, 0, stream>>>(ws + O_EMB, 384, r_wih, 384, r_bih,
                                           ws + O_IH0LN, 1536, 384, 0, nullptr, nullptr, nullptr);
  k_gemm<<<dim3(6, 96), 256, 0, stream>>>(ws + O_EMB, 384, r_proj_w, 768, r_proj_b,
                                          ws + O_KEY0E, 384, 384, 0, nullptr, nullptr, nullptr);
  k_ln_rows<<<6144, 256, 0, stream>>>(ws + O_IH0LN, r_lnih_g, r_lnih_b);
  ScanArgs SA{ws, r_whh, r_bhh, r_lnhh_g, r_lnhh_b, r_lnih_g, r_lnih_b,
              r_lnc_g, r_lnc_b, r_wih, r_bih, r_proj_w, r_proj_b, p_proj_w, p_proj_b};
  k_scan<<<256, 256, 0, stream>>>(SA);
  // head: y = tanh(BN(flat @ p_ffd^T + b)) -> out
  k_gemm<<<dim3(6, 96), 256, 0, stream>>>(ws + O_OUTHS, 768, p_ffd_w, 768, p_ffd_b,
                                          nullptr, 384, 768, 1, p_bn_g, p_bn_b, out);
}

// Round 4
// 13016.136 us; speedup vs baseline: 1.2458x; 1.0105x over previous
//
#include <hip/hip_runtime.h>

// PRPN eval forward for MI355X. All float inputs are FP32, ids int32.
// Output = [y (T*B*D) | mask (T*B)] fp32.
//
// R9 vs R8: same decoupled dual-pipeline DAG, sync mechanics rebuilt.
//  - Flag-slot sync: each producer stores t+1 to its own 64B line (no atomic
//    RMW serialization); waiters gather-read + __all ballot. Monotone ints.
//  - L0/L1/PR are ONE WAVE per batch element (8 wgs x 4 waves each): zero
//    __syncthreads in the per-b chains; vectors in lane-strided float2 regs;
//    reductions via 6-shfl xor ladders; QK via 4-lane-per-slot groups.
//  - Fresh P slot used from registers for the s=14 combine term; mirror
//    write deferred to step tail (no store->load alias stall).
//  - Grid: 8 L0 + 8 L1 + 8 PR + 96 G0 + 64 G1 = 184 wgs, all resident.
//  - Dependency rules (identical to R8, re-verified):
//      L0(t):  G0F >= t          G0(t): L0F >= t+1, L1F >= t-1
//      L1(t):  G0F >= t+1, G1F >= t   G1(t): L1F >= t+1, PRF >= t
//      PR(t):  G1F >= t+1

#define TT 192
#define TB 6144

constexpr size_t O_EMB    = 0;          // T*B*384 fp32
constexpr size_t O_IH0LN  = 2359296;    // T*B*1536 (raw then LN'd in place)
constexpr size_t O_KEY0E  = 11796480;   // T*B*384
constexpr size_t O_MG     = 14155776;   // T*B*15
constexpr size_t O_MGN    = 14247936;   // T*B*15
// ---- dead conv-activation region reused for scan exchange buffers ----
constexpr size_t O_H1     = 14340096;   // B*T x 384 conv acts (pre-scan only)
constexpr size_t O_P0S    = 14340096;   // 32x1536 staging whh0@h0
constexpr size_t O_P1S    = 14389248;   // 32x1536 staging whh1@h1
constexpr size_t O_IH1RAW = 14438400;   // [2] x 32x1536 (parity)
constexpr size_t O_KEY1H  = 14536704;   // [2] x 32x384
constexpr size_t O_KEY0MH = 14561280;   // 32x384
constexpr size_t O_KEY1MH = 14573568;   // 32x384
constexpr size_t O_PKEYH  = 14585856;   // [2] x 32x384
constexpr size_t O_PKEYMH = 14610432;   // [2] x 32x384
constexpr size_t O_HNEW0  = 14635008;   // 32x384
constexpr size_t O_HNEW1  = 14647296;   // [2] x 32x384
constexpr size_t O_BAR    = 14671872;   // flag slots (4096 u32)
constexpr size_t O_DEADEND= 14675968;
// ---------------------------------------------------------------------
constexpr size_t O_GATEA  = 16699392;   // B*T
constexpr size_t O_GATEB  = 16705536;   // B*T
constexpr size_t O_OUTHS  = 16711680;   // T*B x 768 (h | sel)
constexpr size_t O_MEMH0  = 21430272;   // state (zeroed): B x 15 x 384 each
constexpr size_t O_MEMC0  = 21614592;
constexpr size_t O_MEMH1  = 21798912;
constexpr size_t O_MEMC1  = 21983232;
constexpr size_t O_PMEM   = 22167552;
constexpr size_t O_P0     = 22351872;   // P0 mirror: B x 15 x 1536 (wave-private)
constexpr size_t O_P1     = 23089152;   // P1 mirror
constexpr size_t O_STATEEND = 23826432;

// flag slot offsets (u32 units inside BAR; slot stride 16 u32 = 64B)
#define L0F 0
#define L1F 512
#define PRF 1024
#define G0F 1536
#define G1F 3072

__device__ __forceinline__ float sigmoidf(float x) { return 1.f / (1.f + expf(-x)); }

// LLC-coherent relaxed accessors for cross-wg exchange.
__device__ __forceinline__ float ldx(const float* p) {
  return __hip_atomic_load(p, __ATOMIC_RELAXED, __HIP_MEMORY_SCOPE_AGENT);
}
__device__ __forceinline__ void stx(float* p, float v) {
  __hip_atomic_store(p, v, __ATOMIC_RELAXED, __HIP_MEMORY_SCOPE_AGENT);
}
__device__ __forceinline__ float2 ldx2(const float* p) {
  unsigned long long v = __hip_atomic_load((const unsigned long long*)p,
                                           __ATOMIC_RELAXED, __HIP_MEMORY_SCOPE_AGENT);
  return __builtin_bit_cast(float2, v);
}
__device__ __forceinline__ void stx2(float* p, float2 v) {
  __hip_atomic_store((unsigned long long*)p, __builtin_bit_cast(unsigned long long, v),
                     __ATOMIC_RELAXED, __HIP_MEMORY_SCOPE_AGENT);
}
__device__ __forceinline__ int ldi(const int* p) {
  return __hip_atomic_load(p, __ATOMIC_RELAXED, __HIP_MEMORY_SCOPE_AGENT);
}
__device__ __forceinline__ void sti(int* p, int v) {
  __hip_atomic_store(p, v, __ATOMIC_RELAXED, __HIP_MEMORY_SCOPE_AGENT);
}

constexpr float BN_SC = 0.9999950000374997f;       // 1/sqrt(1+1e-5)
constexpr float INV_SQRT_H = 0.05103103630798288f; // 1/sqrt(384)

__device__ __forceinline__ float blockSum(float v, float* red) {
#pragma unroll
  for (int off = 32; off > 0; off >>= 1) v += __shfl_down(v, off, 64);
  __syncthreads();
  if ((threadIdx.x & 63) == 0) red[threadIdx.x >> 6] = v;
  __syncthreads();
  return red[0] + red[1] + red[2] + red[3];
}

__device__ __forceinline__ float2 wred2(float a, float b) {
#pragma unroll
  for (int off = 32; off > 0; off >>= 1) {
    a += __shfl_xor(a, off, 64);
    b += __shfl_xor(b, off, 64);
  }
  return make_float2(a, b);
}

// ---------------------------------------------------------------- k_zero
__global__ __launch_bounds__(256) void k_zero(float* p, int n) {
  int i = blockIdx.x * 256 + threadIdx.x;
  int stride = gridDim.x * 256;
  for (; i < n; i += stride) p[i] = 0.f;
}

// ---------------------------------------------------------------- k_emb (+mask)
__global__ __launch_bounds__(256) void k_emb(const int* ids, const float* emb_w,
                                             float* emb, float* out) {
  size_t idx = (size_t)blockIdx.x * 256 + threadIdx.x;
  size_t stride = (size_t)gridDim.x * 256;
  for (size_t i = idx; i < (size_t)TB * 384; i += stride) {
    size_t tb = i / 384, d = i - tb * 384;
    int id = ids[tb];
    emb[i] = emb_w[(size_t)id * 384 + d];
    if (i < TB) out[(size_t)TB * 384 + i] = (ids[i] != 0) ? 1.f : 0.f;
  }
}

// ---------------------------------------------------------------- k_conv (im2col GEMM)
__global__ __launch_bounds__(256) void k_conv(const float* emb, const float* W1, const float* cbias,
                                              const float* bng, const float* bnb, float* h1) {
  __shared__ float As[32][68];
  __shared__ float Bs[32][68];
  int n0 = blockIdx.x * 64, m0 = blockIdx.y * 64;
  int tid = threadIdx.x;
  float acc[4][4] = {};
  int mi = tid >> 3, kq = tid & 7;
  int ni = tid >> 2, kb = tid & 3;
  for (int kk = 0; kk < 2304; kk += 32) {
    int kc = kk / 384, dbase = kk - kc * 384;
    __syncthreads();
#pragma unroll
    for (int p = 0; p < 2; ++p) {
      int m = m0 + mi + 32 * p;
      int b = m / 192, t = m - b * 192;
      int tt = t + kc - 5;
      float4 v = {0.f, 0.f, 0.f, 0.f};
      if (tt >= 0) v = *(const float4*)(emb + ((size_t)tt * 32 + b) * 384 + dbase + kq * 4);
      As[kq * 4 + 0][mi + 32 * p] = v.x; As[kq * 4 + 1][mi + 32 * p] = v.y;
      As[kq * 4 + 2][mi + 32 * p] = v.z; As[kq * 4 + 3][mi + 32 * p] = v.w;
    }
#pragma unroll
    for (int i = 0; i < 8; ++i) {
      int d = dbase + kb * 8 + i;
      Bs[kb * 8 + i][ni] = W1[(size_t)(n0 + ni) * 2304 + d * 6 + kc];
    }
    __syncthreads();
    int ty = tid >> 4, tx = tid & 15;
#pragma unroll
    for (int k = 0; k < 32; ++k) {
      float4 a = *(const float4*)(&As[k][ty * 4]);
      float4 bv = *(const float4*)(&Bs[k][tx * 4]);
      acc[0][0] += a.x * bv.x; acc[0][1] += a.x * bv.y; acc[0][2] += a.x * bv.z; acc[0][3] += a.x * bv.w;
      acc[1][0] += a.y * bv.x; acc[1][1] += a.y * bv.y; acc[1][2] += a.y * bv.z; acc[1][3] += a.y * bv.w;
      acc[2][0] += a.z * bv.x; acc[2][1] += a.z * bv.y; acc[2][2] += a.z * bv.z; acc[2][3] += a.z * bv.w;
      acc[3][0] += a.w * bv.x; acc[3][1] += a.w * bv.y; acc[3][2] += a.w * bv.z; acc[3][3] += a.w * bv.w;
    }
  }
  int ty = tid >> 4, tx = tid & 15;
#pragma unroll
  for (int i = 0; i < 4; ++i) {
    int m = m0 + ty * 4 + i;
#pragma unroll
    for (int j = 0; j < 4; ++j) {
      int n = n0 + tx * 4 + j;
      float v = acc[i][j] + cbias[n];
      v = bng[n] * v * BN_SC + bnb[n];
      h1[(size_t)m * 384 + n] = fmaxf(v, 0.f);
    }
  }
}

// ---------------------------------------------------------------- k_gate
__global__ __launch_bounds__(256) void k_gate(const float* h1, const float* w2, const float* b2,
                                              float* gA, float* gB) {
  __shared__ float red[8];
  int bt = blockIdx.x, tid = threadIdx.x;
  float v0 = 0.f, v1 = 0.f;
  if (tid < 192) {
    v0 = h1[(size_t)bt * 384 + tid] * w2[tid];
    v1 = h1[(size_t)bt * 384 + 192 + tid] * w2[192 + tid];
  }
  float s0 = blockSum(v0, red);
  float s1 = blockSum(v1, red);
  if (tid == 0) {
    gA[bt] = 1.f / (1.f + expf(-(s0 + b2[0])));
    gB[bt] = 1.f / (1.f + expf(-(s1 + b2[1])));
  }
}

// ---------------------------------------------------------------- k_mg (hard gates + cumprod)
__global__ __launch_bounds__(256) void k_mg(const float* gA, const float* gB, float* mg, float* mgn) {
  int idx = blockIdx.x * 256 + threadIdx.x;
  if (idx >= TB) return;
  int t = idx >> 5, b = idx & 31;
  float g = gA[b * 192 + t], gn = gB[b * 192 + t];
  float p = 1.f, pn = 1.f;
  for (int k = 0; k < 15; ++k) {
    float ghat = (k <= t) ? gA[b * 192 + t - k] : 1e9f;
    float u = fminf(fmaxf((g - ghat) / 0.1f * 2.f + 1.f, -1.f), 1.f);
    float un = fminf(fmaxf((gn - ghat) / 0.1f * 2.f + 1.f, -1.f), 1.f);
    p *= (u + 1.f) * 0.5f;
    pn *= (un + 1.f) * 0.5f;
    mg[(size_t)idx * 15 + k] = p;
    mgn[(size_t)idx * 15 + k] = pn;
  }
}

// ---------------------------------------------------------------- k_gemm (generic)
__global__ __launch_bounds__(256) void k_gemm(const float* A, int lda, const float* W, int ldw,
                                              const float* bias, float* Cf, int ldc, int K, int mode,
                                              const float* bng, const float* bnb, float* Cb) {
  __shared__ float As[32][68];
  __shared__ float Bs[32][68];
  int n0 = blockIdx.x * 64, m0 = blockIdx.y * 64;
  int tid = threadIdx.x;
  float acc[4][4] = {};
  int mi = tid >> 3, kq = tid & 7;
  int ni = tid >> 2, kb = tid & 3;
  for (int kk = 0; kk < K; kk += 32) {
    __syncthreads();
#pragma unroll
    for (int p = 0; p < 2; ++p) {
      int m = m0 + mi + 32 * p;
      float4 v = *(const float4*)(A + (size_t)m * lda + kk + kq * 4);
      As[kq * 4 + 0][mi + 32 * p] = v.x; As[kq * 4 + 1][mi + 32 * p] = v.y;
      As[kq * 4 + 2][mi + 32 * p] = v.z; As[kq * 4 + 3][mi + 32 * p] = v.w;
    }
    {
      const float* wp = W + (size_t)(n0 + ni) * ldw + kk + kb * 8;
      float4 q0 = *(const float4*)(wp);
      float4 q1 = *(const float4*)(wp + 4);
      Bs[kb * 8 + 0][ni] = q0.x; Bs[kb * 8 + 1][ni] = q0.y;
      Bs[kb * 8 + 2][ni] = q0.z; Bs[kb * 8 + 3][ni] = q0.w;
      Bs[kb * 8 + 4][ni] = q1.x; Bs[kb * 8 + 5][ni] = q1.y;
      Bs[kb * 8 + 6][ni] = q1.z; Bs[kb * 8 + 7][ni] = q1.w;
    }
    __syncthreads();
    int ty = tid >> 4, tx = tid & 15;
#pragma unroll
    for (int k = 0; k < 32; ++k) {
      float4 a = *(const float4*)(&As[k][ty * 4]);
      float4 bv = *(const float4*)(&Bs[k][tx * 4]);
      acc[0][0] += a.x * bv.x; acc[0][1] += a.x * bv.y; acc[0][2] += a.x * bv.z; acc[0][3] += a.x * bv.w;
      acc[1][0] += a.y * bv.x; acc[1][1] += a.y * bv.y; acc[1][2] += a.y * bv.z; acc[1][3] += a.y * bv.w;
      acc[2][0] += a.z * bv.x; acc[2][1] += a.z * bv.y; acc[2][2] += a.z * bv.z; acc[2][3] += a.z * bv.w;
      acc[3][0] += a.w * bv.x; acc[3][1] += a.w * bv.y; acc[3][2] += a.w * bv.z; acc[3][3] += a.w * bv.w;
    }
  }
  int ty = tid >> 4, tx = tid & 15;
#pragma unroll
  for (int i = 0; i < 4; ++i) {
    int m = m0 + ty * 4 + i;
#pragma unroll
    for (int j = 0; j < 4; ++j) {
      int n = n0 + tx * 4 + j;
      float v = acc[i][j];
      if (bias) v += bias[n];
      if (mode == 0) Cf[(size_t)m * ldc + n] = v;
      else Cb[(size_t)m * ldc + n] = tanhf(bng[n] * v * BN_SC + bnb[n]);
    }
  }
}

// ---------------------------------------------------------------- k_ln_rows
__global__ __launch_bounds__(256) void k_ln_rows(float* X, const float* g, const float* bt) {
  __shared__ float red[8];
  float* x = X + (size_t)blockIdx.x * 1536;
  int tid = threadIdx.x;
  float ps = 0.f;
  for (int i = tid; i < 1536; i += 256) ps += x[i];
  float mu = blockSum(ps, red) * (1.f / 1536.f);
  ps = 0.f;
  for (int i = tid; i < 1536; i += 256) { float d = x[i] - mu; ps += d * d; }
  float inv = 1.f / (sqrtf(blockSum(ps, red) * (1.f / 1535.f)) + 1e-6f);
  for (int i = tid; i < 1536; i += 256) x[i] = g[i] * (x[i] - mu) * inv + bt[i];
}

// ---------------------------------------------------------------- scan kernel
struct ScanArgs {
  float* ws;
  const float *r_whh, *r_bhh, *r_lnhh_g, *r_lnhh_b, *r_lnih_g, *r_lnih_b;
  const float *r_lnc_g, *r_lnc_b, *r_wih, *r_bih, *r_proj_w, *r_proj_b;
  const float *p_proj_w, *p_proj_b;
};

struct GJob { const float* W; int ldw; int koff; const float* bias; float* dst; int rstride; int ncols; };

__device__ __forceinline__ void resolveJob(const GJob* J, int col, const float*& W, int& ldw, int& koff,
                                           const float*& bias, float*& dst, int& rstride, int& cc) {
  int c = col;
#pragma unroll
  for (int j = 0; j < 4; ++j) {
    if (c < J[j].ncols) {
      W = J[j].W; ldw = J[j].ldw; koff = J[j].koff; bias = J[j].bias;
      dst = J[j].dst; rstride = J[j].rstride; cc = c; return;
    }
    c -= J[j].ncols;
  }
  W = J[0].W; ldw = J[0].ldw; koff = J[0].koff; bias = J[0].bias;
  dst = J[0].dst; rstride = J[0].rstride; cc = 0;
}

// stage x (32x384) into LDS [32][385] via 64-bit LLC loads
__device__ __forceinline__ void stage_x(const float* src, float* xs) {
  const int tid = threadIdx.x;
  for (int j2 = tid; j2 < 6144; j2 += 256) {
    int j = j2 * 2;
    int bb = j / 384, kk = j - bb * 384;
    float2 v = ldx2(src + j);
    xs[bb * 385 + kk] = v.x; xs[bb * 385 + kk + 1] = v.y;
  }
}

// GEMV: ncols cols of the job set, K=384 over 8 thread-groups of 48,
// shfl-pair -> 4 LDS partial rows (stride 33), chunked by 21 cols.
__device__ void gemv_run(const GJob* J, int cbase, int ncols, const float* xs, float* red) {
  const int tid = threadIdx.x;
  const int b = tid & 31, cg = tid >> 5;
  float xr[48];
  const float* xp = xs + b * 385 + cg * 48;
#pragma unroll
  for (int q = 0; q < 48; ++q) xr[q] = xp[q];
  for (int ch = 0; ch < ncols; ch += 21) {
    const int nch = min(21, ncols - ch);
    for (int ci = 0; ci < nch; ++ci) {
      const float* W; int ldw, koff; const float* bias; float* dst; int rstride; int cc;
      resolveJob(J, cbase + ch + ci, W, ldw, koff, bias, dst, rstride, cc);
      const float* wr = W + (size_t)cc * ldw + koff + cg * 48;
      float a = 0.f;
#pragma unroll
      for (int q = 0; q < 12; ++q) {
        float4 w = *(const float4*)(wr + q * 4);
        a += w.x * xr[q * 4 + 0] + w.y * xr[q * 4 + 1]
           + w.z * xr[q * 4 + 2] + w.w * xr[q * 4 + 3];
      }
      a += __shfl_down(a, 32, 64);
      if ((cg & 1) == 0) red[((cg >> 1) * nch + ci) * 33 + b] = a;
    }
    __syncthreads();
    const int pairs = nch * 32;
    for (int pi = tid; pi < pairs; pi += 256) {
      int bb = pi / nch, ci = pi - bb * nch;
      float s = red[(0 * nch + ci) * 33 + bb] + red[(1 * nch + ci) * 33 + bb]
              + red[(2 * nch + ci) * 33 + bb] + red[(3 * nch + ci) * 33 + bb];
      const float* W; int ldw, koff; const float* bias; float* dst; int rstride; int cc;
      resolveJob(J, cbase + ch + ci, W, ldw, koff, bias, dst, rstride, cc);
      if (bias) s += bias[cc];
      stx(dst + (size_t)bb * rstride + cc, s);
    }
    __syncthreads();
  }
}

// wave attention: klds holds the 384-dim key (LDS, wave-private); produces
// att[15] uniform in registers. 4 lanes per slot, 96 dims each.
__device__ __forceinline__ void wave_attn(const float* memh, const float* klds, const float* mgp,
                                          int t, int lane, float (&att)[15]) {
  const int g = lane >> 2, l = lane & 3;
  float part = 0.f;
  if (g < 15) {
    const float* mh = memh + ((t + g) % 15) * 384 + l;
#pragma unroll 8
    for (int k = 0; k < 96; ++k) part += mh[4 * k] * klds[l + 4 * k];
  }
  part += __shfl_xor(part, 1, 64);
  part += __shfl_xor(part, 2, 64);
  float logit[15];
#pragma unroll
  for (int s = 0; s < 15; ++s) logit[s] = __shfl(part, 4 * s, 64) * INV_SQRT_H;
  float m = logit[0];
#pragma unroll
  for (int s = 1; s < 15; ++s) m = fmaxf(m, logit[s]);
  float sum = 0.f;
#pragma unroll
  for (int s = 0; s < 15; ++s) { att[s] = expf(logit[s] - m) * mgp[s]; sum += att[s]; }
  float inv = 1.f / (sum + 1e-8f);
#pragma unroll
  for (int s = 0; s < 15; ++s) att[s] *= inv;
}

// ================= L0: one wave per b =================
__device__ void l0_loop(int b, int lane, float* klds, const ScanArgs& A, int* bar) {
  float* ws = A.ws;
  float* memh = ws + O_MEMH0 + (size_t)b * 5760;
  float* memc = ws + O_MEMC0 + (size_t)b * 5760;
  float* mir  = ws + O_P0 + (size_t)b * 23040;
  const float* stg = ws + O_P0S + (size_t)b * 1536;
  const int* p1 = bar + G0F + lane * 16;
  const int* p2 = bar + G0F + (64 + (lane & 31)) * 16;
  for (int t = 0; t < 192; ++t) {
    const size_t tb = (size_t)t * 32 + b;
    // issue stream loads before the poll (latency hides under the wait)
    float2 ih[12];
#pragma unroll
    for (int j = 0; j < 12; ++j)
      ih[j] = *(const float2*)(ws + O_IH0LN + tb * 1536 + 2 * lane + 128 * j);
    float2 kE[3];
#pragma unroll
    for (int j = 0; j < 3; ++j)
      kE[j] = *(const float2*)(ws + O_KEY0E + tb * 384 + 2 * lane + 128 * j);
    // wait G0(t-1) done
    while (true) {
      int a = ldi(p1);
      int c = (lane < 32) ? ldi(p2) : 0x7fffffff;
      if (__all(a >= t && c >= t)) break;
      __builtin_amdgcn_s_sleep(1);
    }
    // pulls: fresh P slot (regs), key
    float2 fresh[12];
#pragma unroll
    for (int j = 0; j < 12; ++j) fresh[j] = ldx2(stg + 2 * lane + 128 * j);
#pragma unroll
    for (int j = 0; j < 3; ++j) {
      float2 c2 = ldx2(ws + O_KEY0MH + (size_t)b * 384 + 2 * lane + 128 * j);
      *(float2*)(klds + 2 * lane + 128 * j) = make_float2(kE[j].x + c2.x, kE[j].y + c2.y);
    }
    float att[15];
    wave_attn(memh, klds, ws + O_MG + tb * 15, t, lane, att);
    // combine ghh: s=0..13 from mirror, s=14 is the fresh slot (registers)
    float2 acc[12];
#pragma unroll
    for (int j = 0; j < 12; ++j) {
      float2 bb = *(const float2*)(A.r_bhh + 2 * lane + 128 * j);
      acc[j] = make_float2(bb.x + att[14] * fresh[j].x, bb.y + att[14] * fresh[j].y);
    }
#pragma unroll
    for (int s = 0; s < 14; ++s) {
      const float* P = mir + ((t + s) % 15) * 1536;
      float a = att[s];
#pragma unroll
      for (int j = 0; j < 12; ++j) {
        float2 p = *(const float2*)(P + 2 * lane + 128 * j);
        acc[j].x += a * p.x; acc[j].y += a * p.y;
      }
    }
    float2 selc[3];
#pragma unroll
    for (int j = 0; j < 3; ++j) selc[j] = make_float2(0.f, 0.f);
#pragma unroll
    for (int s = 0; s < 15; ++s) {
      const float* C = memc + ((t + s) % 15) * 384;
      float a = att[s];
#pragma unroll
      for (int j = 0; j < 3; ++j) {
        float2 p = *(const float2*)(C + 2 * lane + 128 * j);
        selc[j].x += a * p.x; selc[j].y += a * p.y;
      }
    }
    // LN(ghh)
    float s1 = 0.f, s2 = 0.f;
#pragma unroll
    for (int j = 0; j < 12; ++j) {
      s1 += acc[j].x + acc[j].y;
      s2 += acc[j].x * acc[j].x + acc[j].y * acc[j].y;
    }
    float2 r = wred2(s1, s2);
    float mu = r.x * (1.f / 1536.f);
    float inv = 1.f / (sqrtf(fmaxf(r.y - r.x * mu, 0.f) * (1.f / 1535.f)) + 1e-6f);
    // gates + cell
    const float* hg = A.r_lnhh_g;
    const float* hb = A.r_lnhh_b;
    float2 cn[3], og[3];
#pragma unroll
    for (int jj = 0; jj < 3; ++jj) {
      const int d = 2 * lane + 128 * jj;
      float2 gi, gf, gc, go;
      { float2 g2 = *(const float2*)(hg + d), b2 = *(const float2*)(hb + d);
        gi.x = ih[jj].x + g2.x * (acc[jj].x - mu) * inv + b2.x;
        gi.y = ih[jj].y + g2.y * (acc[jj].y - mu) * inv + b2.y; }
      { float2 g2 = *(const float2*)(hg + 384 + d), b2 = *(const float2*)(hb + 384 + d);
        gf.x = ih[3 + jj].x + g2.x * (acc[3 + jj].x - mu) * inv + b2.x;
        gf.y = ih[3 + jj].y + g2.y * (acc[3 + jj].y - mu) * inv + b2.y; }
      { float2 g2 = *(const float2*)(hg + 768 + d), b2 = *(const float2*)(hb + 768 + d);
        gc.x = ih[6 + jj].x + g2.x * (acc[6 + jj].x - mu) * inv + b2.x;
        gc.y = ih[6 + jj].y + g2.y * (acc[6 + jj].y - mu) * inv + b2.y; }
      { float2 g2 = *(const float2*)(hg + 1152 + d), b2 = *(const float2*)(hb + 1152 + d);
        go.x = ih[9 + jj].x + g2.x * (acc[9 + jj].x - mu) * inv + b2.x;
        go.y = ih[9 + jj].y + g2.y * (acc[9 + jj].y - mu) * inv + b2.y; }
      cn[jj].x = sigmoidf(gf.x) * selc[jj].x + sigmoidf(gi.x) * tanhf(gc.x);
      cn[jj].y = sigmoidf(gf.y) * selc[jj].y + sigmoidf(gi.y) * tanhf(gc.y);
      og[jj] = go;
    }
    // LN(c)
    s1 = 0.f; s2 = 0.f;
#pragma unroll
    for (int jj = 0; jj < 3; ++jj) {
      s1 += cn[jj].x + cn[jj].y;
      s2 += cn[jj].x * cn[jj].x + cn[jj].y * cn[jj].y;
    }
    r = wred2(s1, s2);
    float mu_c = r.x * (1.f / 384.f);
    float inv_c = 1.f / (sqrtf(fmaxf(r.y - r.x * mu_c, 0.f) * (1.f / 383.f)) + 1e-6f);
    const int slot = t % 15;
    const int pslot = (t + 14) % 15;
#pragma unroll
    for (int jj = 0; jj < 3; ++jj) {
      const int d = 2 * lane + 128 * jj;
      float2 lg2 = *(const float2*)(A.r_lnc_g + d), lb2 = *(const float2*)(A.r_lnc_b + d);
      float2 hn;
      hn.x = sigmoidf(og[jj].x) * tanhf(lg2.x * (cn[jj].x - mu_c) * inv_c + lb2.x);
      hn.y = sigmoidf(og[jj].y) * tanhf(lg2.y * (cn[jj].y - mu_c) * inv_c + lb2.y);
      *(float2*)(memh + slot * 384 + d) = hn;
      *(float2*)(memc + slot * 384 + d) = cn[jj];
      stx2(ws + O_HNEW0 + (size_t)b * 384 + d, hn);
    }
#pragma unroll
    for (int j = 0; j < 12; ++j)
      *(float2*)(mir + pslot * 1536 + 2 * lane + 128 * j) = fresh[j];
    asm volatile("s_waitcnt vmcnt(0)" ::: "memory");
    if (lane == 0) sti(bar + L0F + b * 16, t + 1);
  }
}

// ================= L1: one wave per b =================
__device__ void l1_loop(int b, int lane, float* klds, const ScanArgs& A, int* bar) {
  float* ws = A.ws;
  float* memh = ws + O_MEMH1 + (size_t)b * 5760;
  float* memc = ws + O_MEMC1 + (size_t)b * 5760;
  float* mir  = ws + O_P1 + (size_t)b * 23040;
  const float* stg = ws + O_P1S + (size_t)b * 1536;
  const float* hg = A.r_lnhh_g + 1536;
  const float* hb = A.r_lnhh_b + 1536;
  const float* igp = A.r_lnih_g + 1536;
  const float* ibp = A.r_lnih_b + 1536;
  const float* bhh = A.r_bhh + 1536;
  const float* lcg = A.r_lnc_g + 384;
  const float* lcb = A.r_lnc_b + 384;
  const int* p1 = bar + G0F + lane * 16;
  const int* p2 = bar + G0F + (64 + (lane & 31)) * 16;
  const int* p3 = bar + G1F + lane * 16;
  for (int t = 0; t < 192; ++t) {
    while (true) {
      int a = ldi(p1);
      int c = (lane < 32) ? ldi(p2) : 0x7fffffff;
      int d2 = ldi(p3);
      if (__all(a >= t + 1 && c >= t + 1 && d2 >= t)) break;
      __builtin_amdgcn_s_sleep(1);
    }
    const size_t tb = (size_t)t * 32 + b;
    const size_t par = (size_t)(t & 1);
    float2 gx[12], fresh[12];
#pragma unroll
    for (int j = 0; j < 12; ++j) {
      gx[j] = ldx2(ws + O_IH1RAW + par * 49152 + (size_t)b * 1536 + 2 * lane + 128 * j);
      fresh[j] = ldx2(stg + 2 * lane + 128 * j);
    }
#pragma unroll
    for (int j = 0; j < 3; ++j) {
      float2 a2 = ldx2(ws + O_KEY1H + par * 12288 + (size_t)b * 384 + 2 * lane + 128 * j);
      float2 c2 = ldx2(ws + O_KEY1MH + (size_t)b * 384 + 2 * lane + 128 * j);
      *(float2*)(klds + 2 * lane + 128 * j) = make_float2(a2.x + c2.x, a2.y + c2.y);
    }
    float att[15];
    wave_attn(memh, klds, ws + O_MG + tb * 15, t, lane, att);
    float2 acc[12];
#pragma unroll
    for (int j = 0; j < 12; ++j) {
      float2 bb = *(const float2*)(bhh + 2 * lane + 128 * j);
      acc[j] = make_float2(bb.x + att[14] * fresh[j].x, bb.y + att[14] * fresh[j].y);
    }
#pragma unroll
    for (int s = 0; s < 14; ++s) {
      const float* P = mir + ((t + s) % 15) * 1536;
      float a = att[s];
#pragma unroll
      for (int j = 0; j < 12; ++j) {
        float2 p = *(const float2*)(P + 2 * lane + 128 * j);
        acc[j].x += a * p.x; acc[j].y += a * p.y;
      }
    }
    float2 selc[3];
#pragma unroll
    for (int j = 0; j < 3; ++j) selc[j] = make_float2(0.f, 0.f);
#pragma unroll
    for (int s = 0; s < 15; ++s) {
      const float* C = memc + ((t + s) % 15) * 384;
      float a = att[s];
#pragma unroll
      for (int j = 0; j < 3; ++j) {
        float2 p = *(const float2*)(C + 2 * lane + 128 * j);
        selc[j].x += a * p.x; selc[j].y += a * p.y;
      }
    }
    // LN(gih)
    float s1 = 0.f, s2 = 0.f;
#pragma unroll
    for (int j = 0; j < 12; ++j) {
      s1 += gx[j].x + gx[j].y;
      s2 += gx[j].x * gx[j].x + gx[j].y * gx[j].y;
    }
    float2 r = wred2(s1, s2);
    float mu_i = r.x * (1.f / 1536.f);
    float inv_i = 1.f / (sqrtf(fmaxf(r.y - r.x * mu_i, 0.f) * (1.f / 1535.f)) + 1e-6f);
    // LN(ghh)
    s1 = 0.f; s2 = 0.f;
#pragma unroll
    for (int j = 0; j < 12; ++j) {
      s1 += acc[j].x + acc[j].y;
      s2 += acc[j].x * acc[j].x + acc[j].y * acc[j].y;
    }
    r = wred2(s1, s2);
    float mu = r.x * (1.f / 1536.f);
    float inv = 1.f / (sqrtf(fmaxf(r.y - r.x * mu, 0.f) * (1.f / 1535.f)) + 1e-6f);
    float2 cn[3], og[3];
#pragma unroll
    for (int jj = 0; jj < 3; ++jj) {
      const int d = 2 * lane + 128 * jj;
      float2 gi, gf, gc, go;
      { float2 i2 = *(const float2*)(igp + d), ib2 = *(const float2*)(ibp + d);
        float2 g2 = *(const float2*)(hg + d), b2 = *(const float2*)(hb + d);
        gi.x = i2.x * (gx[jj].x - mu_i) * inv_i + ib2.x + g2.x * (acc[jj].x - mu) * inv + b2.x;
        gi.y = i2.y * (gx[jj].y - mu_i) * inv_i + ib2.y + g2.y * (acc[jj].y - mu) * inv + b2.y; }
      { float2 i2 = *(const float2*)(igp + 384 + d), ib2 = *(const float2*)(ibp + 384 + d);
        float2 g2 = *(const float2*)(hg + 384 + d), b2 = *(const float2*)(hb + 384 + d);
        gf.x = i2.x * (gx[3 + jj].x - mu_i) * inv_i + ib2.x + g2.x * (acc[3 + jj].x - mu) * inv + b2.x;
        gf.y = i2.y * (gx[3 + jj].y - mu_i) * inv_i + ib2.y + g2.y * (acc[3 + jj].y - mu) * inv + b2.y; }
      { float2 i2 = *(const float2*)(igp + 768 + d), ib2 = *(const float2*)(ibp + 768 + d);
        float2 g2 = *(const float2*)(hg + 768 + d), b2 = *(const float2*)(hb + 768 + d);
        gc.x = i2.x * (gx[6 + jj].x - mu_i) * inv_i + ib2.x + g2.x * (acc[6 + jj].x - mu) * inv + b2.x;
        gc.y = i2.y * (gx[6 + jj].y - mu_i) * inv_i + ib2.y + g2.y * (acc[6 + jj].y - mu) * inv + b2.y; }
      { float2 i2 = *(const float2*)(igp + 1152 + d), ib2 = *(const float2*)(ibp + 1152 + d);
        float2 g2 = *(const float2*)(hg + 1152 + d), b2 = *(const float2*)(hb + 1152 + d);
        go.x = i2.x * (gx[9 + jj].x - mu_i) * inv_i + ib2.x + g2.x * (acc[9 + jj].x - mu) * inv + b2.x;
        go.y = i2.y * (gx[9 + jj].y - mu_i) * inv_i + ib2.y + g2.y * (acc[9 + jj].y - mu) * inv + b2.y; }
      cn[jj].x = sigmoidf(gf.x) * selc[jj].x + sigmoidf(gi.x) * tanhf(gc.x);
      cn[jj].y = sigmoidf(gf.y) * selc[jj].y + sigmoidf(gi.y) * tanhf(gc.y);
      og[jj] = go;
    }
    s1 = 0.f; s2 = 0.f;
#pragma unroll
    for (int jj = 0; jj < 3; ++jj) {
      s1 += cn[jj].x + cn[jj].y;
      s2 += cn[jj].x * cn[jj].x + cn[jj].y * cn[jj].y;
    }
    r = wred2(s1, s2);
    float mu_c = r.x * (1.f / 384.f);
    float inv_c = 1.f / (sqrtf(fmaxf(r.y - r.x * mu_c, 0.f) * (1.f / 383.f)) + 1e-6f);
    const int slot = t % 15;
    const int pslot = (t + 14) % 15;
#pragma unroll
    for (int jj = 0; jj < 3; ++jj) {
      const int d = 2 * lane + 128 * jj;
      float2 lg2 = *(const float2*)(lcg + d), lb2 = *(const float2*)(lcb + d);
      float2 hn;
      hn.x = sigmoidf(og[jj].x) * tanhf(lg2.x * (cn[jj].x - mu_c) * inv_c + lb2.x);
      hn.y = sigmoidf(og[jj].y) * tanhf(lg2.y * (cn[jj].y - mu_c) * inv_c + lb2.y);
      *(float2*)(memh + slot * 384 + d) = hn;
      *(float2*)(memc + slot * 384 + d) = cn[jj];
      stx2(ws + O_HNEW1 + par * 12288 + (size_t)b * 384 + d, hn);
      *(float2*)(ws + O_OUTHS + tb * 768 + d) = hn;
    }
#pragma unroll
    for (int j = 0; j < 12; ++j)
      *(float2*)(mir + pslot * 1536 + 2 * lane + 128 * j) = fresh[j];
    asm volatile("s_waitcnt vmcnt(0)" ::: "memory");
    if (lane == 0) sti(bar + L1F + b * 16, t + 1);
  }
}

// ================= PR: one wave per b =================
__device__ void pr_loop(int b, int lane, float* klds, const ScanArgs& A, int* bar) {
  float* ws = A.ws;
  float* pmem = ws + O_PMEM + (size_t)b * 5760;
  const int* p1 = bar + G1F + lane * 16;
  for (int t = 0; t < 192; ++t) {
    while (true) {
      int a = ldi(p1);
      if (__all(a >= t + 1)) break;
      __builtin_amdgcn_s_sleep(1);
    }
    const size_t tb = (size_t)t * 32 + b;
#pragma unroll
    for (int j = 0; j < 3; ++j) {
      float2 a2 = ldx2(ws + O_PKEYH + (size_t)(t & 1) * 12288 + (size_t)b * 384 + 2 * lane + 128 * j);
      float2 c2 = ldx2(ws + O_PKEYMH + (size_t)((t + 1) & 1) * 12288 + (size_t)b * 384 + 2 * lane + 128 * j);
      *(float2*)(klds + 2 * lane + 128 * j) = make_float2(a2.x + c2.x, a2.y + c2.y);
    }
    float att[15];
    wave_attn(pmem, klds, ws + O_MGN + tb * 15, t, lane, att);
    float2 sel[3];
#pragma unroll
    for (int j = 0; j < 3; ++j) sel[j] = make_float2(0.f, 0.f);
#pragma unroll
    for (int s = 0; s < 15; ++s) {
      const float* P = pmem + ((t + s) % 15) * 384;
      float a = att[s];
#pragma unroll
      for (int j = 0; j < 3; ++j) {
        float2 p = *(const float2*)(P + 2 * lane + 128 * j);
        sel[j].x += a * p.x; sel[j].y += a * p.y;
      }
    }
#pragma unroll
    for (int j = 0; j < 3; ++j)
      *(float2*)(ws + O_OUTHS + tb * 768 + 384 + 2 * lane + 128 * j) = sel[j];
    // append h1(t) into the oldest slot (reads of that slot already consumed)
#pragma unroll
    for (int j = 0; j < 3; ++j) {
      float2 v = ldx2(ws + O_HNEW1 + (size_t)(t & 1) * 12288 + (size_t)b * 384 + 2 * lane + 128 * j);
      *(float2*)(pmem + (t % 15) * 384 + 2 * lane + 128 * j) = v;
    }
    asm volatile("s_waitcnt vmcnt(0)" ::: "memory");
    if (lane == 0) sti(bar + PRF + b * 16, t + 1);
  }
}

// ================= GEMV domains =================
__device__ void g0_loop(int gwg, const ScanArgs& A, int* bar, float* sm) {
  float* ws = A.ws;
  const int tid = threadIdx.x;
  float* xs = sm;
  float* red = sm + 12320;
  const int cbase = gwg * 40;
  for (int t = 0; t < 192; ++t) {
    if (tid < 64) {
      const int* p = (tid < 32) ? (bar + L0F + tid * 16) : (bar + L1F + (tid - 32) * 16);
      const int tgt = (tid < 32) ? (t + 1) : (t - 1);
      while (true) {
        int v = ldi(p);
        if (__all(v >= tgt)) break;
        __builtin_amdgcn_s_sleep(1);
      }
    }
    __syncthreads();
    stage_x(ws + O_HNEW0, xs);
    __syncthreads();
    const size_t par = (size_t)(t & 1);
    GJob J[4] = {
      { A.r_wih + 589824, 384, 0, A.r_bih + 1536, ws + O_IH1RAW + par * 49152, 1536, 1536 },
      { A.r_proj_w + 294912, 768, 0, A.r_proj_b + 384, ws + O_KEY1H + par * 12288, 384, 384 },
      { A.r_whh, 384, 0, nullptr, ws + O_P0S, 1536, 1536 },
      { A.r_proj_w, 768, 384, nullptr, ws + O_KEY0MH, 384, 384 },
    };
    gemv_run(J, cbase, 40, xs, red);
    if (tid == 0) sti(bar + G0F + gwg * 16, t + 1);
  }
}

__device__ void g1_loop(int gwg, const ScanArgs& A, int* bar, float* sm) {
  float* ws = A.ws;
  const int tid = threadIdx.x;
  float* xs = sm;
  float* red = sm + 12320;
  const int cbase = gwg * 42;
  for (int t = 0; t < 192; ++t) {
    if (tid < 64) {
      const int* p = (tid < 32) ? (bar + L1F + tid * 16) : (bar + PRF + (tid - 32) * 16);
      const int tgt = (tid < 32) ? (t + 1) : t;
      while (true) {
        int v = ldi(p);
        if (__all(v >= tgt)) break;
        __builtin_amdgcn_s_sleep(1);
      }
    }
    __syncthreads();
    const size_t par = (size_t)(t & 1);
    stage_x(ws + O_HNEW1 + par * 12288, xs);
    __syncthreads();
    GJob J[4] = {
      { A.r_whh + 589824, 384, 0, nullptr, ws + O_P1S, 1536, 1536 },
      { A.r_proj_w + 294912, 768, 384, nullptr, ws + O_KEY1MH, 384, 384 },
      { A.p_proj_w, 768, 0, A.p_proj_b, ws + O_PKEYH + par * 12288, 384, 384 },
      { A.p_proj_w, 768, 384, nullptr, ws + O_PKEYMH + par * 12288, 384, 384 },
    };
    gemv_run(J, cbase, 42, xs, red);
    if (tid == 0) sti(bar + G1F + gwg * 16, t + 1);
  }
}

// grid: 8 L0 | 8 L1 | 8 PR | 96 G0 | 64 G1  = 184 wgs
__global__ __launch_bounds__(256) void k_scan(ScanArgs A) {
  __shared__ float sm[15104];           // L-classes: klds 4x384 | GEMV: xs 12320 + red 2772
  int* bar = (int*)(A.ws + O_BAR);
  const int wg = blockIdx.x;
  const int tid = threadIdx.x;
  const int lane = tid & 63;
  const int wv = tid >> 6;
  if (wg < 8)        l0_loop(wg * 4 + wv, lane, sm + wv * 384, A, bar);
  else if (wg < 16)  l1_loop((wg - 8) * 4 + wv, lane, sm + wv * 384, A, bar);
  else if (wg < 24)  pr_loop((wg - 16) * 4 + wv, lane, sm + wv * 384, A, bar);
  else if (wg < 120) g0_loop(wg - 24, A, bar, sm);
  else               g1_loop(wg - 120, A, bar, sm);
}

// ---------------------------------------------------------------- launch
extern "C" void kernel_launch(void* const* d_in, const int* in_sizes, int n_in,
                              void* d_out, int out_size, void* d_ws, size_t ws_size,
                              hipStream_t stream) {
  const int* ids = (const int*)d_in[0];
  const float* emb_w = (const float*)d_in[1];
  const float* pconv1_w = (const float*)d_in[2];
  const float* pconv1_b = (const float*)d_in[3];
  const float* pbn_g = (const float*)d_in[4];
  const float* pbn_b = (const float*)d_in[5];
  const float* pconv2_w = (const float*)d_in[6];
  const float* pconv2_b = (const float*)d_in[7];
  const float* r_wih = (const float*)d_in[8];
  const float* r_bih = (const float*)d_in[9];
  const float* r_whh = (const float*)d_in[10];
  const float* r_bhh = (const float*)d_in[11];
  const float* r_lnih_g = (const float*)d_in[12];
  const float* r_lnih_b = (const float*)d_in[13];
  const float* r_lnhh_g = (const float*)d_in[14];
  const float* r_lnhh_b = (const float*)d_in[15];
  const float* r_lnc_g = (const float*)d_in[16];
  const float* r_lnc_b = (const float*)d_in[17];
  const float* r_proj_w = (const float*)d_in[18];
  const float* r_proj_b = (const float*)d_in[19];
  const float* p_proj_w = (const float*)d_in[20];
  const float* p_proj_b = (const float*)d_in[21];
  const float* p_ffd_w = (const float*)d_in[22];
  const float* p_ffd_b = (const float*)d_in[23];
  const float* p_bn_g = (const float*)d_in[24];
  const float* p_bn_b = (const float*)d_in[25];
  float* ws = (float*)d_ws;
  float* out = (float*)d_out;

  k_zero<<<1024, 256, 0, stream>>>(ws + O_MEMH0, (int)(O_STATEEND - O_MEMH0));
  k_emb<<<4096, 256, 0, stream>>>(ids, emb_w, ws + O_EMB, out);
  k_conv<<<dim3(6, 96), 256, 0, stream>>>(ws + O_EMB, pconv1_w, pconv1_b, pbn_g, pbn_b, ws + O_H1);
  k_gate<<<6144, 256, 0, stream>>>(ws + O_H1, pconv2_w, pconv2_b, ws + O_GATEA, ws + O_GATEB);
  k_mg<<<24, 256, 0, stream>>>(ws + O_GATEA, ws + O_GATEB, ws + O_MG, ws + O_MGN);
  // exchange buffers + flags live in the (now dead) conv-activation region
  k_zero<<<328, 256, 0, stream>>>(ws + O_P0S, (int)(O_DEADEND - O_P0S));
  // precompute LN(e@Wih0+b) and key0_e = e@proj0_h + b for all t
  k_gemm<<<dim3(24, 96), 256, 0, stream>>>(ws + O_EMB, 384, r_wih, 384, r_bih,
                                           ws + O_IH0LN, 1536, 384, 0, nullptr, nullptr, nullptr);
  k_gemm<<<dim3(6, 96), 256, 0, stream>>>(ws + O_EMB, 384, r_proj_w, 768, r_proj_b,
                                          ws + O_KEY0E, 384, 384, 0, nullptr, nullptr, nullptr);
  k_ln_rows<<<6144, 256, 0, stream>>>(ws + O_IH0LN, r_lnih_g, r_lnih_b);
  ScanArgs SA{ws, r_whh, r_bhh, r_lnhh_g, r_lnhh_b, r_lnih_g, r_lnih_b,
              r_lnc_g, r_lnc_b, r_wih, r_bih, r_proj_w, r_proj_b, p_proj_w, p_proj_b};
  k_scan<<<184, 256, 0, stream>>>(SA);
  // head: y = tanh(BN(flat @ p_ffd^T + b)) -> out
  k_gemm<<<dim3(6, 96), 256, 0, stream>>>(ws + O_OUTHS, 768, p_ffd_w, 768, p_ffd_b,
                                          nullptr, 384, 768, 1, p_bn_g, p_bn_b, out);
}